// Round 16
// baseline (115.848 us; speedup 1.0000x reference)
//
#include <hip/hip_runtime.h>
#include <math.h>

#define HW 4096
#define NB 8
#define NK 19
#define CIN 512
#define CTC 256

typedef __attribute__((ext_vector_type(8))) short short8;
typedef __attribute__((ext_vector_type(4))) float f32x4;

__device__ inline unsigned short f2bf(float x) {
  unsigned u = __float_as_uint(x);
  return (unsigned short)((u + 0x7fffu + ((u >> 16) & 1u)) >> 16);  // RNE
}
__device__ inline float bf2f(unsigned short h) {
  return __uint_as_float(((unsigned)h) << 16);
}
__device__ inline void gload16(const void* g, void* l) {
  __builtin_amdgcn_global_load_lds(
      (const __attribute__((address_space(1))) void*)g,
      (__attribute__((address_space(3))) void*)l, 16, 0, 0);
}

// ---------------------------------------------------------------------------
// wk1a (verified round 12): weight convert + cls_feat zero + k1a partials.
// ---------------------------------------------------------------------------
__global__ __launch_bounds__(256) void wk1a(
    const float* __restrict__ w1, const float* __restrict__ w2,
    const float* __restrict__ wo, unsigned short* __restrict__ wb1,
    unsigned short* __restrict__ wb2, unsigned short* __restrict__ wbo,
    uint4* __restrict__ cls_feat_z, const float* __restrict__ preds,
    float* __restrict__ bestg, int* __restrict__ clsg,
    unsigned int* __restrict__ Mu_part, unsigned int* __restrict__ cnt_part) {
  __shared__ unsigned int Mw[NK];
  __shared__ unsigned int Cw[NK];
  int bx = blockIdx.x;
  int tid = threadIdx.x;
  if (bx < 320) {
    int gid = bx * 256 + tid;
    int i = gid * 4;  // [0, 327680)
    const float* src;
    unsigned short* dst;
    int off;
    if (i < 131072) { src = w1; dst = wb1; off = i; }
    else if (i < 196608) { src = w2; dst = wb2; off = i - 131072; }
    else { src = wo; dst = wbo; off = i - 196608; }
    float4 v = *(const float4*)(src + off);
    dst[off + 0] = f2bf(v.x);
    dst[off + 1] = f2bf(v.y);
    dst[off + 2] = f2bf(v.z);
    dst[off + 3] = f2bf(v.w);
    uint4 z = {0u, 0u, 0u, 0u};
    for (int j = gid; j < 19456; j += 81920) cls_feat_z[j] = z;
  } else {
    int bq = bx - 320;
    int b = bq >> 4, pblk = bq & 15;
    if (tid < NK) { Mw[tid] = 0u; Cw[tid] = 0u; }
    __syncthreads();
    int p = pblk * 256 + tid;
    const float* pb = preds + (size_t)b * NK * HW;
    float best = pb[p];
    int bi = 0;
#pragma unroll
    for (int k = 1; k < NK; ++k) {
      float v = pb[k * HW + p];
      if (v > best) { best = v; bi = k; }  // strict > = jnp.argmax first-index
    }
    bestg[b * HW + p] = best;
    clsg[b * HW + p] = bi;
    unsigned fb = __float_as_uint(best);
    unsigned key = (fb & 0x80000000u) ? ~fb : (fb | 0x80000000u);
    atomicMax(&Mw[bi], key);
    atomicAdd(&Cw[bi], 1u);
    __syncthreads();
    if (tid < 32) {
      Mu_part[(b * 16 + pblk) * 32 + tid] = (tid < NK) ? Mw[tid] : 0u;
      cnt_part[(b * 16 + pblk) * 32 + tid] = (tid < NK) ? Cw[tid] : 0u;
    }
  }
}

// ---------------------------------------------------------------------------
// k1b (verified round 12).
// ---------------------------------------------------------------------------
__global__ __launch_bounds__(256) void k1b(
    float* __restrict__ bestg, const int* __restrict__ clsg,
    const unsigned int* __restrict__ Mu_part, float* __restrict__ Zf_part) {
  int b = blockIdx.y, pblk = blockIdx.x;
  int tid = threadIdx.x;
  __shared__ float Mf[NK];
  __shared__ float Zw[NK];
  if (tid < NK) {
    unsigned key = 0u;
#pragma unroll
    for (int j = 0; j < 16; ++j) {
      unsigned v = Mu_part[(b * 16 + j) * 32 + tid];
      key = (v > key) ? v : key;
    }
    float m = -1e30f;
    if (key) {
      unsigned fb = (key & 0x80000000u) ? (key & 0x7fffffffu) : ~key;
      m = __uint_as_float(fb);
    }
    Mf[tid] = m;
    Zw[tid] = 0.f;
  }
  __syncthreads();
  int p = pblk * 256 + tid;
  int c = clsg[b * HW + p];
  float e = expf(bestg[b * HW + p] - Mf[c]);
  bestg[b * HW + p] = e;
  atomicAdd(&Zw[c], e);
  __syncthreads();
  if (tid < 32) Zf_part[(b * 16 + pblk) * 32 + tid] = (tid < NK) ? Zw[tid] : 0.f;
}

// ---------------------------------------------------------------------------
// FUSED xk2 (verified round 12).
// ---------------------------------------------------------------------------
__global__ __launch_bounds__(256) void xk2(
    const float* __restrict__ x, const float* __restrict__ eg,
    const int* __restrict__ clsg, const float* __restrict__ Zf_part,
    unsigned short* __restrict__ xT, float* __restrict__ cls_feat) {
  __shared__ float tile[64][65];
  __shared__ unsigned short Bs[32 * 516];
  __shared__ float Zl[NK];
  int b = blockIdx.z, c0 = blockIdx.y * 64, pbase = blockIdx.x * 512;
  int tid = threadIdx.x;
  int l = tid & 63, w = tid >> 6;
  if (tid < NK) {
    float s = 0.f;
#pragma unroll
    for (int j = 0; j < 16; ++j) s += Zf_part[(b * 16 + j) * 32 + tid];
    Zl[tid] = s;
  }
  {
    uint4 z = {0u, 0u, 0u, 0u};
    for (int i = tid; i < 2064; i += 256) ((uint4*)Bs)[i] = z;
  }
  __syncthreads();
  for (int i = tid; i < 512; i += 256) {
    int c = clsg[b * HW + pbase + i];
    Bs[c * 516 + i] = f2bf(eg[b * HW + pbase + i] / Zl[c]);
  }
  f32x4 acc[2];
  acc[0] = (f32x4){0.f, 0.f, 0.f, 0.f};
  acc[1] = (f32x4){0.f, 0.f, 0.f, 0.f};
  int cbase = w * 16;
  for (int s = 0; s < 8; ++s) {
    int ps = pbase + s * 64;
    __syncthreads();
#pragma unroll
    for (int r = 0; r < 4; ++r) {
      int cl = r * 16 + (tid >> 4);
      int pl = (tid & 15) * 4;
      float4 v = *(const float4*)&x[((size_t)b * CIN + c0 + cl) * HW + ps + pl];
      tile[cl][pl + 0] = v.x;
      tile[cl][pl + 1] = v.y;
      tile[cl][pl + 2] = v.z;
      tile[cl][pl + 3] = v.w;
    }
    __syncthreads();
#pragma unroll
    for (int j = 0; j < 16; ++j) {
      int ploc = j * 4 + w;
      xT[((size_t)b * HW + ps + ploc) * CIN + c0 + l] = f2bf(tile[l][ploc]);
    }
#pragma unroll
    for (int ch = 0; ch < 2; ++ch) {
      int pt = ch * 32 + (l >> 4) * 8;
      union { short8 v; unsigned short u[8]; } af;
      const float* tp = &tile[cbase + (l & 15)][pt];
#pragma unroll
      for (int j = 0; j < 8; ++j) af.u[j] = f2bf(tp[j]);
      int pg = s * 64 + pt;
#pragma unroll
      for (int mf = 0; mf < 2; ++mf) {
        short8 bf = *(const short8*)&Bs[(mf * 16 + (l & 15)) * 516 + pg];
        acc[mf] =
            __builtin_amdgcn_mfma_f32_16x16x32_bf16(af.v, bf, acc[mf], 0, 0, 0);
      }
    }
  }
#pragma unroll
  for (int mf = 0; mf < 2; ++mf) {
    int k = mf * 16 + (l & 15);
    if (k < NK) {
#pragma unroll
      for (int r = 0; r < 4; ++r) {
        int c = c0 + cbase + (l >> 4) * 4 + r;
        atomicAdd(&cls_feat[((size_t)b * NK + k) * CIN + c], acc[mf][r]);
      }
    }
  }
}

// ---------------------------------------------------------------------------
// K3a / K3b (verified round 7).
// ---------------------------------------------------------------------------
__global__ __launch_bounds__(256) void k3a(
    const float* __restrict__ cls_feat, const float* __restrict__ kw1,
    const float* __restrict__ kg1, const float* __restrict__ kb1,
    const float* __restrict__ vw, const float* __restrict__ vg,
    const float* __restrict__ vb, float* __restrict__ h1g,
    float* __restrict__ Vcls) {
  int bk = blockIdx.y;
  int b = bk / NK, kc = bk % NK;
  int q = blockIdx.x;
  __shared__ float cf[CIN];
  int tid = threadIdx.x;
  const float* row = cls_feat + (size_t)bk * CIN;
  for (int i = tid; i < CIN; i += 256) cf[i] = row[i];
  __syncthreads();
  int o = tid >> 1, half = tid & 1;
  int col = q * 64 + (o & 63);
  const float* w =
      (o < 64) ? &kw1[(size_t)col * CIN] : &vw[(size_t)col * CIN];
  int base = half * 256;
  float acc[4] = {0.f, 0.f, 0.f, 0.f};
#pragma unroll 8
  for (int i = 0; i < 64; ++i) {
    float4 w4 = *(const float4*)&w[base + i * 4];
    const float* c4 = &cf[base + i * 4];
    acc[i & 3] += w4.x * c4[0] + w4.y * c4[1] + w4.z * c4[2] + w4.w * c4[3];
  }
  float s = (acc[0] + acc[1]) + (acc[2] + acc[3]);
  s += __shfl_xor(s, 1);
  if (half == 0) {
    if (o < 64) {
      h1g[(size_t)bk * CTC + col] = fmaxf(s * kg1[col] + kb1[col], 0.f);
    } else {
      Vcls[((size_t)b * CTC + col) * NK + kc] =
          fmaxf(s * vg[col] + vb[col], 0.f);
    }
  }
}

__global__ __launch_bounds__(256) void k3b(
    const float* __restrict__ h1g, const float* __restrict__ kw2,
    const float* __restrict__ kg2, const float* __restrict__ kb2,
    unsigned short* __restrict__ KclsT) {
  int bk = blockIdx.y;
  int q = blockIdx.x;
  __shared__ float h1[CTC];
  int tid = threadIdx.x;
  const float* row = h1g + (size_t)bk * CTC;
  if (tid < CTC) h1[tid] = row[tid];
  __syncthreads();
  int o = tid >> 2, part = tid & 3;
  int col = q * 64 + o;
  const float* w = &kw2[(size_t)col * CTC + part * 64];
  const float* c = &h1[part * 64];
  float acc[4] = {0.f, 0.f, 0.f, 0.f};
#pragma unroll
  for (int i = 0; i < 16; ++i) {
    float4 w4 = *(const float4*)&w[i * 4];
    acc[i & 3] += w4.x * c[i * 4] + w4.y * c[i * 4 + 1] + w4.z * c[i * 4 + 2] +
                  w4.w * c[i * 4 + 3];
  }
  float s = (acc[0] + acc[1]) + (acc[2] + acc[3]);
  s += __shfl_xor(s, 1);
  s += __shfl_xor(s, 2);
  if (part == 0)
    KclsT[(size_t)bk * CTC + col] = f2bf(fmaxf(s * kg2[col] + kb2[col], 0.f));
}

// ---------------------------------------------------------------------------
// FUSED g1g2k5o — 64-pixel tile, 256 threads / 4 waves, ~78 KB LDS ->
// 2 blocks/CU (barrier stalls of one block hidden by the other).
// Region R is time-multiplexed: As+Bs dbuf (1a/1b) -> Kl2+Vl2+simT+Pl (2-4,
// staged after Bs dies) -> WoBuf dbuf (stage 5, M split in two 256-halves,
// half-0 stores overlap half-1 staging). Per-pixel math identical to r15.
// ---------------------------------------------------------------------------
__global__ __launch_bounds__(256, 2) void g1g2k5o(
    const unsigned short* __restrict__ xT, const unsigned short* __restrict__ W1,
    const float* __restrict__ g1, const float* __restrict__ b1,
    const unsigned short* __restrict__ W2, const float* __restrict__ g2,
    const float* __restrict__ b2, const unsigned short* __restrict__ KclsT,
    const float* __restrict__ Vcls, const unsigned int* __restrict__ cnt_part,
    const unsigned short* __restrict__ Wo, const float* __restrict__ og,
    const float* __restrict__ ob, float* __restrict__ out) {
  __shared__ __align__(16) char SMQ[32768];  // Q1f: q1 -> q2 -> ctx
  __shared__ __align__(16) char SMR[45568];  // As+Bs | Kl2+Vl2+simT+Pl | WoBuf
  __shared__ float cntl[NK];
  unsigned short* Q1f = (unsigned short*)SMQ;           // [8][64p*32ch swz]
  unsigned short* As = (unsigned short*)SMR;            // [2][64*32]
  unsigned short* Bs = (unsigned short*)(SMR + 8192);   // [2][256*32]
  unsigned short* Kl2 = (unsigned short*)SMR;           // [32s][32m][8]
  unsigned short* Vl2 = (unsigned short*)(SMR + 16384); // [4s][256c][8]
  float* simT = (float*)(SMR + 32768);                  // [64][33]
  unsigned short* Pl = (unsigned short*)(SMR + 41216);  // [4s][64p][8]
  unsigned short* WoBuf = (unsigned short*)SMR;         // [2][256*32]

  int b = blockIdx.y;
  int p0 = blockIdx.x * 64;
  int tid = threadIdx.x;
  int l = tid & 63, w = tid >> 6;  // 4 waves
  int wp = w & 1, wm = w >> 1;     // 32-pixel strip x 128-channel half
  const unsigned short* xTb = xT + ((size_t)b * HW + p0) * CIN;

  if (tid < NK) {
    unsigned int s = 0u;
#pragma unroll
    for (int j = 0; j < 16; ++j) s += cnt_part[(b * 16 + j) * 32 + tid];
    cntl[tid] = (float)s;
  }

  f32x4 acc[2][8];

  // ---- stage 1a: q1 = relu(g1*(W1 . xT)+b1), K=512 ----
  auto STAGE_A1 = [&](int buf, int t) {  // 4 KB: 1 gload/thread
    int k0 = t * 32;
    int e = tid * 8;
    int rl = e >> 5, sl = (e >> 3) & 3;
    gload16(xTb + (size_t)rl * CIN + k0 + 8 * (sl ^ ((rl >> 1) & 3)),
            &As[buf * 2048 + w * 512]);
  };
  auto STAGE_B1 = [&](int buf, int t) {  // 16 KB: 4 gloads/thread
    int k0 = t * 32;
#pragma unroll
    for (int q = 0; q < 4; ++q) {
      int e = q * 2048 + tid * 8;
      int rl = e >> 5, sl = (e >> 3) & 3;
      gload16(W1 + (size_t)rl * CIN + k0 + 8 * (sl ^ ((rl >> 1) & 3)),
              &Bs[buf * 8192 + q * 2048 + w * 512]);
    }
  };
#pragma unroll
  for (int i = 0; i < 2; ++i)
#pragma unroll
    for (int j = 0; j < 8; ++j) acc[i][j] = (f32x4){0.f, 0.f, 0.f, 0.f};
  STAGE_A1(0, 0);
  STAGE_B1(0, 0);
  for (int t = 0; t < 16; ++t) {
    __syncthreads();
    if (t + 1 < 16) { STAGE_A1((t + 1) & 1, t + 1); STAGE_B1((t + 1) & 1, t + 1); }
    int cur = t & 1;
    short8 af[2];
#pragma unroll
    for (int f = 0; f < 2; ++f) {
      int nl = wp * 32 + f * 16 + (l & 15);
      af[f] =
          *(const short8*)&As[cur * 2048 + nl * 32 + 8 * ((l >> 4) ^ ((nl >> 1) & 3))];
    }
#pragma unroll
    for (int mf = 0; mf < 8; ++mf) {
      int ml = wm * 128 + mf * 16 + (l & 15);
      short8 bf =
          *(const short8*)&Bs[cur * 8192 + ml * 32 + 8 * ((l >> 4) ^ ((ml >> 1) & 3))];
      acc[0][mf] =
          __builtin_amdgcn_mfma_f32_16x16x32_bf16(af[0], bf, acc[0][mf], 0, 0, 0);
      acc[1][mf] =
          __builtin_amdgcn_mfma_f32_16x16x32_bf16(af[1], bf, acc[1][mf], 0, 0, 0);
    }
  }
  // epilogue: q1 -> Q1f (verified chunk-swizzle write; rows now 64p)
#pragma unroll
  for (int mf = 0; mf < 8; ++mf) {
    int ch = wm * 128 + mf * 16 + (l & 15);
    float gm = g1[ch], bm = b1[ch];
    int tq = ch >> 5, slot = (ch >> 3) & 3, wi = ch & 7;
#pragma unroll
    for (int i = 0; i < 2; ++i) {
#pragma unroll
      for (int r = 0; r < 4; ++r) {
        int p = wp * 32 + i * 16 + (l >> 4) * 4 + r;
        Q1f[tq * 2048 + p * 32 + 8 * (slot ^ ((p >> 1) & 3)) + wi] =
            f2bf(fmaxf(acc[i][mf][r] * gm + bm, 0.f));
      }
    }
  }

  // ---- stage 1b: q2 = relu(g2*(W2 . q1)+b2), K=256, A from Q1f ----
  auto STAGE_B2 = [&](int buf, int t) {
    int k0 = t * 32;
#pragma unroll
    for (int q = 0; q < 4; ++q) {
      int e = q * 2048 + tid * 8;
      int rl = e >> 5, sl = (e >> 3) & 3;
      gload16(W2 + (size_t)rl * CTC + k0 + 8 * (sl ^ ((rl >> 1) & 3)),
              &Bs[buf * 8192 + q * 2048 + w * 512]);
    }
  };
#pragma unroll
  for (int i = 0; i < 2; ++i)
#pragma unroll
    for (int j = 0; j < 8; ++j) acc[i][j] = (f32x4){0.f, 0.f, 0.f, 0.f};
  STAGE_B2(0, 0);
  for (int t = 0; t < 8; ++t) {
    __syncthreads();  // Q1f visible (t=0); Bs[cur] staged; prev Bs reads done
    if (t + 1 < 8) STAGE_B2((t + 1) & 1, t + 1);
    int cur = t & 1;
    short8 af[2];
#pragma unroll
    for (int f = 0; f < 2; ++f) {
      int nl = wp * 32 + f * 16 + (l & 15);
      af[f] =
          *(const short8*)&Q1f[t * 2048 + nl * 32 + 8 * ((l >> 4) ^ ((nl >> 1) & 3))];
    }
#pragma unroll
    for (int mf = 0; mf < 8; ++mf) {
      int ml = wm * 128 + mf * 16 + (l & 15);
      short8 bf =
          *(const short8*)&Bs[cur * 8192 + ml * 32 + 8 * ((l >> 4) ^ ((ml >> 1) & 3))];
      acc[0][mf] =
          __builtin_amdgcn_mfma_f32_16x16x32_bf16(af[0], bf, acc[0][mf], 0, 0, 0);
      acc[1][mf] =
          __builtin_amdgcn_mfma_f32_16x16x32_bf16(af[1], bf, acc[1][mf], 0, 0, 0);
    }
  }
  __syncthreads();  // all Q1f(q1) reads + Bs reads done
  // epilogue: q2 -> Q1f overlay
#pragma unroll
  for (int mf = 0; mf < 8; ++mf) {
    int ch = wm * 128 + mf * 16 + (l & 15);
    float gm = g2[ch], bm = b2[ch];
    int tq = ch >> 5, slot = (ch >> 3) & 3, wi = ch & 7;
#pragma unroll
    for (int i = 0; i < 2; ++i) {
#pragma unroll
      for (int r = 0; r < 4; ++r) {
        int p = wp * 32 + i * 16 + (l >> 4) * 4 + r;
        Q1f[tq * 2048 + p * 32 + 8 * (slot ^ ((p >> 1) & 3)) + wi] =
            f2bf(fmaxf(acc[i][mf][r] * gm + bm, 0.f));
      }
    }
  }
  // stage Kl2/Vl2 into R (As/Bs dead after the barrier above)
  for (int i = tid; i < NK * 32; i += 256) {
    int m = i >> 5, s = i & 31;
    short8 v = *(const short8*)&KclsT[((size_t)b * NK + m) * CTC + s * 8];
    *(short8*)&Kl2[(s * 32 + m) * 8] = v;
  }
  for (int i = tid; i < 4 * 256; i += 256) {
    int s = i >> 8, c = i & 255;
    union { short8 v; unsigned short u[8]; } pk;
    const float* vr = &Vcls[((size_t)b * CTC + c) * NK];
#pragma unroll
    for (int j = 0; j < 8; ++j) {
      int k = s * 8 + j;
      pk.u[j] = (k < NK) ? f2bf(vr[k]) : (unsigned short)0;
    }
    *(short8*)&Vl2[(s * 256 + c) * 8] = pk.v;
  }
  __syncthreads();  // Qf(q2) + Kl2 + Vl2 visible

  // ---- stage 2: sim = q2 . Kcls (4 waves x 16 pixels) ----
  f32x4 a2[2];
  a2[0] = (f32x4){0.f, 0.f, 0.f, 0.f};
  a2[1] = (f32x4){0.f, 0.f, 0.f, 0.f};
  for (int t = 0; t < 8; ++t) {
    int nl = w * 16 + (l & 15);
    short8 aq =
        *(const short8*)&Q1f[t * 2048 + nl * 32 + 8 * ((l >> 4) ^ ((nl >> 1) & 3))];
    int s = t * 4 + (l >> 4);
#pragma unroll
    for (int j = 0; j < 2; ++j) {
      int ml = j * 16 + (l & 15);
      short8 bk = *(const short8*)&Kl2[(s * 32 + ml) * 8];
      a2[j] = __builtin_amdgcn_mfma_f32_16x16x32_bf16(aq, bk, a2[j], 0, 0, 0);
    }
  }
  __syncthreads();  // Kl2 reads done (simT region is disjoint; sync for order)
#pragma unroll
  for (int j = 0; j < 2; ++j) {
    int m = j * 16 + (l & 15);
    if (m < NK) {
#pragma unroll
      for (int r = 0; r < 4; ++r) {
        int p = w * 16 + (l >> 4) * 4 + r;
        simT[p * 33 + m] = a2[j][r];
      }
    }
  }
  __syncthreads();
  if (tid < 64) {
    float sims[NK];
#pragma unroll
    for (int k = 0; k < NK; ++k) sims[k] = simT[tid * 33 + k] * 0.0625f;
    float m = -1e30f;
#pragma unroll
    for (int k = 0; k < NK; ++k)
      if (cntl[k] > 0.f) m = fmaxf(m, sims[k]);
    float d = 0.f;
#pragma unroll
    for (int k = 0; k < NK; ++k) {
      float e = (cntl[k] > 0.f) ? expf(sims[k] - m) : 0.f;
      sims[k] = cntl[k] * e;
      d += sims[k];
    }
    float inv = 1.f / d;
#pragma unroll
    for (int s = 0; s < 4; ++s) {
      union { short8 v; unsigned short u8[8]; } pk;
#pragma unroll
      for (int j = 0; j < 8; ++j) {
        int k = s * 8 + j;
        pk.u8[j] = (k < NK) ? f2bf(sims[k] * inv) : (unsigned short)0;
      }
      *(short8*)&Pl[(s * 64 + tid) * 8] = pk.v;
    }
  }
  __syncthreads();
  // ---- stage 4: PV -> ctx bf16 -> Q1f ----
  short8 ap;
  {
    int nl = w * 16 + (l & 15);
    ap = *(const short8*)&Pl[((l >> 4) * 64 + nl) * 8];
  }
#pragma unroll
  for (int mc = 0; mc < 4; ++mc) {
#pragma unroll
    for (int mf = 0; mf < 4; ++mf) {
      int ml = mc * 64 + mf * 16 + (l & 15);
      short8 bv = *(const short8*)&Vl2[((l >> 4) * 256 + ml) * 8];
      f32x4 z = {0.f, 0.f, 0.f, 0.f};
      f32x4 o = __builtin_amdgcn_mfma_f32_16x16x32_bf16(ap, bv, z, 0, 0, 0);
      int tq = ml >> 5, slot = (ml >> 3) & 3, wi = ml & 7;
#pragma unroll
      for (int r = 0; r < 4; ++r) {
        int p = w * 16 + (l >> 4) * 4 + r;
        Q1f[tq * 2048 + p * 32 + 8 * (slot ^ ((p >> 1) & 3)) + wi] = f2bf(o[r]);
      }
    }
  }

  // ---- stage 5: out = relu(og*(Wo . ctx)+ob), K=256, M=512 in 2 halves ----
  auto STAGE_WO = [&](int hm, int buf, int t) {  // 16 KB: 4 gloads/thread
    int k0 = t * 32;
#pragma unroll
    for (int q = 0; q < 4; ++q) {
      int e = q * 2048 + tid * 8;
      int rl = e >> 5, sl = (e >> 3) & 3;
      gload16(Wo + (size_t)(hm * 256 + rl) * CTC + k0 + 8 * (sl ^ ((rl >> 1) & 3)),
              &WoBuf[buf * 8192 + q * 2048 + w * 512]);
    }
  };
  float* outb = out + (size_t)b * CIN * HW;
  // prologue: WoBuf[0] overlays Kl2 (dead: all Kl2 reads barrier'd in stage 2/3)
  STAGE_WO(0, 0, 0);
  for (int hm = 0; hm < 2; ++hm) {
#pragma unroll
    for (int i = 0; i < 2; ++i)
#pragma unroll
      for (int j = 0; j < 8; ++j) acc[i][j] = (f32x4){0.f, 0.f, 0.f, 0.f};
    for (int t = 0; t < 8; ++t) {
      __syncthreads();  // t=0(hm=0): PV Q1f writes + Pl/Vl2 reads complete
      if (t + 1 < 8) STAGE_WO(hm, (t + 1) & 1, t + 1);
      int cur = t & 1;
      short8 af[2];
#pragma unroll
      for (int f = 0; f < 2; ++f) {
        int nl = wp * 32 + f * 16 + (l & 15);
        af[f] =
            *(const short8*)&Q1f[t * 2048 + nl * 32 + 8 * ((l >> 4) ^ ((nl >> 1) & 3))];
      }
#pragma unroll
      for (int mf = 0; mf < 8; ++mf) {
        int ml = wm * 128 + mf * 16 + (l & 15);  // row within the 256-half
        short8 bf =
            *(const short8*)&WoBuf[cur * 8192 + ml * 32 + 8 * ((l >> 4) ^ ((ml >> 1) & 3))];
        acc[0][mf] =
            __builtin_amdgcn_mfma_f32_16x16x32_bf16(af[0], bf, acc[0][mf], 0, 0, 0);
        acc[1][mf] =
            __builtin_amdgcn_mfma_f32_16x16x32_bf16(af[1], bf, acc[1][mf], 0, 0, 0);
      }
    }
    // issue next half's first staging (buf0 last read at t=6, synced at t=7's
    // barrier) so half-0 stores overlap it
    if (hm == 0) STAGE_WO(1, 0, 0);
    // stores: f32 float4 (same mapping as verified gemm outmode 0)
#pragma unroll
    for (int mf = 0; mf < 8; ++mf) {
      int co = hm * 256 + wm * 128 + mf * 16 + (l & 15);
      float gm = og[co], bm = ob[co];
#pragma unroll
      for (int i = 0; i < 2; ++i) {
        int n = p0 + wp * 32 + i * 16 + (l >> 4) * 4;
        float4 o;
        o.x = fmaxf(acc[i][mf][0] * gm + bm, 0.f);
        o.y = fmaxf(acc[i][mf][1] * gm + bm, 0.f);
        o.z = fmaxf(acc[i][mf][2] * gm + bm, 0.f);
        o.w = fmaxf(acc[i][mf][3] * gm + bm, 0.f);
        *(float4*)&outb[(size_t)co * HW + n] = o;
      }
    }
  }
}

// ---------------------------------------------------------------------------
extern "C" void kernel_launch(void* const* d_in, const int* in_sizes, int n_in,
                              void* d_out, int out_size, void* d_ws, size_t ws_size,
                              hipStream_t stream) {
  const float* x = (const float*)d_in[0];
  const float* preds = (const float*)d_in[1];
  const float* q_w1 = (const float*)d_in[3];
  const float* q_g1 = (const float*)d_in[4];
  const float* q_b1 = (const float*)d_in[5];
  const float* q_w2 = (const float*)d_in[6];
  const float* q_g2 = (const float*)d_in[7];
  const float* q_b2 = (const float*)d_in[8];
  const float* k_w1 = (const float*)d_in[9];
  const float* k_g1 = (const float*)d_in[10];
  const float* k_b1 = (const float*)d_in[11];
  const float* k_w2 = (const float*)d_in[12];
  const float* k_g2 = (const float*)d_in[13];
  const float* k_b2 = (const float*)d_in[14];
  const float* v_w = (const float*)d_in[15];
  const float* v_g = (const float*)d_in[16];
  const float* v_b = (const float*)d_in[17];
  const float* o_w = (const float*)d_in[18];
  const float* o_g = (const float*)d_in[19];
  const float* o_b = (const float*)d_in[20];
  float* out = (float*)d_out;

  char* base = (char*)d_ws;
  unsigned short* xT = (unsigned short*)base;               // 33,554,432 B
  char* f32r = base + 33554432;
  float* cls_feat = (float*)f32r;                            // 311,296 B
  unsigned short* KclsT = (unsigned short*)(f32r + 311296);  // 77,824 B
  float* Vcls = (float*)(f32r + 389120);                     // 155,648 B
  unsigned short* wb1 = (unsigned short*)(f32r + 544768);    // 262,144 B
  unsigned short* wb2 = (unsigned short*)(f32r + 806912);    // 131,072 B
  unsigned short* wbo = (unsigned short*)(f32r + 937984);    // 262,144 B
  float* h1g = (float*)(f32r + 1200128);                     // 155,648 B
  float* bestg = (float*)(f32r + 1355776);                   // 131,072 B
  int* clsg = (int*)(f32r + 1486848);                        // 131,072 B
  unsigned int* Mu_part = (unsigned int*)(f32r + 1617920);   // 16,384 B
  unsigned int* cnt_part = (unsigned int*)(f32r + 1634304);  // 16,384 B
  float* Zf_part = (float*)(f32r + 1650688);                 // 16,384 B

  wk1a<<<448, 256, 0, stream>>>(q_w1, q_w2, o_w, wb1, wb2, wbo,
                                (uint4*)cls_feat, preds, bestg, clsg, Mu_part,
                                cnt_part);
  k1b<<<dim3(16, NB), 256, 0, stream>>>(bestg, clsg, Mu_part, Zf_part);
  xk2<<<dim3(8, 8, NB), 256, 0, stream>>>(x, bestg, clsg, Zf_part, xT,
                                          cls_feat);
  k3a<<<dim3(4, NB * NK), 256, 0, stream>>>(cls_feat, k_w1, k_g1, k_b1, v_w,
                                            v_g, v_b, h1g, Vcls);
  k3b<<<dim3(4, NB * NK), 256, 0, stream>>>(h1g, k_w2, k_g2, k_b2, KclsT);
  g1g2k5o<<<dim3(HW / 64, NB), 256, 0, stream>>>(xT, wb1, q_g1, q_b1, wb2,
                                                 q_g2, q_b2, KclsT, Vcls,
                                                 cnt_part, wbo, o_g, o_b,
                                                 out);
}

// Round 17
// 112.700 us; speedup vs baseline: 1.0279x; 1.0279x over previous
//
#include <hip/hip_runtime.h>
#include <math.h>

#define HW 4096
#define NB 8
#define NK 19
#define CIN 512
#define CTC 256

typedef __attribute__((ext_vector_type(8))) short short8;
typedef __attribute__((ext_vector_type(4))) float f32x4;

__device__ inline unsigned short f2bf(float x) {
  unsigned u = __float_as_uint(x);
  return (unsigned short)((u + 0x7fffu + ((u >> 16) & 1u)) >> 16);  // RNE
}
__device__ inline float bf2f(unsigned short h) {
  return __uint_as_float(((unsigned)h) << 16);
}
__device__ inline void gload16(const void* g, void* l) {
  __builtin_amdgcn_global_load_lds(
      (const __attribute__((address_space(1))) void*)g,
      (__attribute__((address_space(3))) void*)l, 16, 0, 0);
}

// ---------------------------------------------------------------------------
// wk1a (verified round 12): weight convert + cls_feat zero + k1a partials.
// ---------------------------------------------------------------------------
__global__ __launch_bounds__(256) void wk1a(
    const float* __restrict__ w1, const float* __restrict__ w2,
    const float* __restrict__ wo, unsigned short* __restrict__ wb1,
    unsigned short* __restrict__ wb2, unsigned short* __restrict__ wbo,
    uint4* __restrict__ cls_feat_z, const float* __restrict__ preds,
    float* __restrict__ bestg, int* __restrict__ clsg,
    unsigned int* __restrict__ Mu_part, unsigned int* __restrict__ cnt_part) {
  __shared__ unsigned int Mw[NK];
  __shared__ unsigned int Cw[NK];
  int bx = blockIdx.x;
  int tid = threadIdx.x;
  if (bx < 320) {
    int gid = bx * 256 + tid;
    int i = gid * 4;  // [0, 327680)
    const float* src;
    unsigned short* dst;
    int off;
    if (i < 131072) { src = w1; dst = wb1; off = i; }
    else if (i < 196608) { src = w2; dst = wb2; off = i - 131072; }
    else { src = wo; dst = wbo; off = i - 196608; }
    float4 v = *(const float4*)(src + off);
    dst[off + 0] = f2bf(v.x);
    dst[off + 1] = f2bf(v.y);
    dst[off + 2] = f2bf(v.z);
    dst[off + 3] = f2bf(v.w);
    uint4 z = {0u, 0u, 0u, 0u};
    for (int j = gid; j < 19456; j += 81920) cls_feat_z[j] = z;
  } else {
    int bq = bx - 320;
    int b = bq >> 4, pblk = bq & 15;
    if (tid < NK) { Mw[tid] = 0u; Cw[tid] = 0u; }
    __syncthreads();
    int p = pblk * 256 + tid;
    const float* pb = preds + (size_t)b * NK * HW;
    float best = pb[p];
    int bi = 0;
#pragma unroll
    for (int k = 1; k < NK; ++k) {
      float v = pb[k * HW + p];
      if (v > best) { best = v; bi = k; }  // strict > = jnp.argmax first-index
    }
    bestg[b * HW + p] = best;
    clsg[b * HW + p] = bi;
    unsigned fb = __float_as_uint(best);
    unsigned key = (fb & 0x80000000u) ? ~fb : (fb | 0x80000000u);
    atomicMax(&Mw[bi], key);
    atomicAdd(&Cw[bi], 1u);
    __syncthreads();
    if (tid < 32) {
      Mu_part[(b * 16 + pblk) * 32 + tid] = (tid < NK) ? Mw[tid] : 0u;
      cnt_part[(b * 16 + pblk) * 32 + tid] = (tid < NK) ? Cw[tid] : 0u;
    }
  }
}

// ---------------------------------------------------------------------------
// k1b (verified round 12).
// ---------------------------------------------------------------------------
__global__ __launch_bounds__(256) void k1b(
    float* __restrict__ bestg, const int* __restrict__ clsg,
    const unsigned int* __restrict__ Mu_part, float* __restrict__ Zf_part) {
  int b = blockIdx.y, pblk = blockIdx.x;
  int tid = threadIdx.x;
  __shared__ float Mf[NK];
  __shared__ float Zw[NK];
  if (tid < NK) {
    unsigned key = 0u;
#pragma unroll
    for (int j = 0; j < 16; ++j) {
      unsigned v = Mu_part[(b * 16 + j) * 32 + tid];
      key = (v > key) ? v : key;
    }
    float m = -1e30f;
    if (key) {
      unsigned fb = (key & 0x80000000u) ? (key & 0x7fffffffu) : ~key;
      m = __uint_as_float(fb);
    }
    Mf[tid] = m;
    Zw[tid] = 0.f;
  }
  __syncthreads();
  int p = pblk * 256 + tid;
  int c = clsg[b * HW + p];
  float e = expf(bestg[b * HW + p] - Mf[c]);
  bestg[b * HW + p] = e;
  atomicAdd(&Zw[c], e);
  __syncthreads();
  if (tid < 32) Zf_part[(b * 16 + pblk) * 32 + tid] = (tid < NK) ? Zw[tid] : 0.f;
}

// ---------------------------------------------------------------------------
// FUSED xk2 (verified round 12).
// ---------------------------------------------------------------------------
__global__ __launch_bounds__(256) void xk2(
    const float* __restrict__ x, const float* __restrict__ eg,
    const int* __restrict__ clsg, const float* __restrict__ Zf_part,
    unsigned short* __restrict__ xT, float* __restrict__ cls_feat) {
  __shared__ float tile[64][65];
  __shared__ unsigned short Bs[32 * 516];
  __shared__ float Zl[NK];
  int b = blockIdx.z, c0 = blockIdx.y * 64, pbase = blockIdx.x * 512;
  int tid = threadIdx.x;
  int l = tid & 63, w = tid >> 6;
  if (tid < NK) {
    float s = 0.f;
#pragma unroll
    for (int j = 0; j < 16; ++j) s += Zf_part[(b * 16 + j) * 32 + tid];
    Zl[tid] = s;
  }
  {
    uint4 z = {0u, 0u, 0u, 0u};
    for (int i = tid; i < 2064; i += 256) ((uint4*)Bs)[i] = z;
  }
  __syncthreads();
  for (int i = tid; i < 512; i += 256) {
    int c = clsg[b * HW + pbase + i];
    Bs[c * 516 + i] = f2bf(eg[b * HW + pbase + i] / Zl[c]);
  }
  f32x4 acc[2];
  acc[0] = (f32x4){0.f, 0.f, 0.f, 0.f};
  acc[1] = (f32x4){0.f, 0.f, 0.f, 0.f};
  int cbase = w * 16;
  for (int s = 0; s < 8; ++s) {
    int ps = pbase + s * 64;
    __syncthreads();
#pragma unroll
    for (int r = 0; r < 4; ++r) {
      int cl = r * 16 + (tid >> 4);
      int pl = (tid & 15) * 4;
      float4 v = *(const float4*)&x[((size_t)b * CIN + c0 + cl) * HW + ps + pl];
      tile[cl][pl + 0] = v.x;
      tile[cl][pl + 1] = v.y;
      tile[cl][pl + 2] = v.z;
      tile[cl][pl + 3] = v.w;
    }
    __syncthreads();
#pragma unroll
    for (int j = 0; j < 16; ++j) {
      int ploc = j * 4 + w;
      xT[((size_t)b * HW + ps + ploc) * CIN + c0 + l] = f2bf(tile[l][ploc]);
    }
#pragma unroll
    for (int ch = 0; ch < 2; ++ch) {
      int pt = ch * 32 + (l >> 4) * 8;
      union { short8 v; unsigned short u[8]; } af;
      const float* tp = &tile[cbase + (l & 15)][pt];
#pragma unroll
      for (int j = 0; j < 8; ++j) af.u[j] = f2bf(tp[j]);
      int pg = s * 64 + pt;
#pragma unroll
      for (int mf = 0; mf < 2; ++mf) {
        short8 bf = *(const short8*)&Bs[(mf * 16 + (l & 15)) * 516 + pg];
        acc[mf] =
            __builtin_amdgcn_mfma_f32_16x16x32_bf16(af.v, bf, acc[mf], 0, 0, 0);
      }
    }
  }
#pragma unroll
  for (int mf = 0; mf < 2; ++mf) {
    int k = mf * 16 + (l & 15);
    if (k < NK) {
#pragma unroll
      for (int r = 0; r < 4; ++r) {
        int c = c0 + cbase + (l >> 4) * 4 + r;
        atomicAdd(&cls_feat[((size_t)b * NK + k) * CIN + c], acc[mf][r]);
      }
    }
  }
}

// ---------------------------------------------------------------------------
// K3a (verified round 7) — NOW writes VclsP pre-packed bf16 in Vl2's
// slot-major layout: VclsP[b][(kc>>3)*256 + col][kc&7]. Same f2bf(relu(...))
// values as the old staging path -> numerics identical.
// ---------------------------------------------------------------------------
__global__ __launch_bounds__(256) void k3a(
    const float* __restrict__ cls_feat, const float* __restrict__ kw1,
    const float* __restrict__ kg1, const float* __restrict__ kb1,
    const float* __restrict__ vw, const float* __restrict__ vg,
    const float* __restrict__ vb, float* __restrict__ h1g,
    unsigned short* __restrict__ VclsP) {
  int bk = blockIdx.y;
  int b = bk / NK, kc = bk % NK;
  int q = blockIdx.x;
  __shared__ float cf[CIN];
  int tid = threadIdx.x;
  const float* row = cls_feat + (size_t)bk * CIN;
  for (int i = tid; i < CIN; i += 256) cf[i] = row[i];
  __syncthreads();
  int o = tid >> 1, half = tid & 1;
  int col = q * 64 + (o & 63);
  const float* w =
      (o < 64) ? &kw1[(size_t)col * CIN] : &vw[(size_t)col * CIN];
  int base = half * 256;
  float acc[4] = {0.f, 0.f, 0.f, 0.f};
#pragma unroll 8
  for (int i = 0; i < 64; ++i) {
    float4 w4 = *(const float4*)&w[base + i * 4];
    const float* c4 = &cf[base + i * 4];
    acc[i & 3] += w4.x * c4[0] + w4.y * c4[1] + w4.z * c4[2] + w4.w * c4[3];
  }
  float s = (acc[0] + acc[1]) + (acc[2] + acc[3]);
  s += __shfl_xor(s, 1);
  if (half == 0) {
    if (o < 64) {
      h1g[(size_t)bk * CTC + col] = fmaxf(s * kg1[col] + kb1[col], 0.f);
    } else {
      VclsP[(size_t)b * 8192 + ((kc >> 3) * 256 + col) * 8 + (kc & 7)] =
          f2bf(fmaxf(s * vg[col] + vb[col], 0.f));
    }
  }
}

// ---------------------------------------------------------------------------
// K3b (verified round 7) — NOW writes KclsP pre-packed bf16 in Kl2's
// slot-major layout: KclsP[b][(col>>3)*32 + kc][col&7].
// ---------------------------------------------------------------------------
__global__ __launch_bounds__(256) void k3b(
    const float* __restrict__ h1g, const float* __restrict__ kw2,
    const float* __restrict__ kg2, const float* __restrict__ kb2,
    unsigned short* __restrict__ KclsP) {
  int bk = blockIdx.y;
  int b = bk / NK, kc = bk % NK;
  int q = blockIdx.x;
  __shared__ float h1[CTC];
  int tid = threadIdx.x;
  const float* row = h1g + (size_t)bk * CTC;
  if (tid < CTC) h1[tid] = row[tid];
  __syncthreads();
  int o = tid >> 2, part = tid & 3;
  int col = q * 64 + o;
  const float* w = &kw2[(size_t)col * CTC + part * 64];
  const float* c = &h1[part * 64];
  float acc[4] = {0.f, 0.f, 0.f, 0.f};
#pragma unroll
  for (int i = 0; i < 16; ++i) {
    float4 w4 = *(const float4*)&w[i * 4];
    acc[i & 3] += w4.x * c[i * 4] + w4.y * c[i * 4 + 1] + w4.z * c[i * 4 + 2] +
                  w4.w * c[i * 4 + 3];
  }
  float s = (acc[0] + acc[1]) + (acc[2] + acc[3]);
  s += __shfl_xor(s, 1);
  s += __shfl_xor(s, 2);
  if (part == 0)
    KclsP[(size_t)b * 8192 + ((col >> 3) * 32 + kc) * 8 + (col & 7)] =
        f2bf(fmaxf(s * kg2[col] + kb2[col], 0.f));
}

// ---------------------------------------------------------------------------
// FUSED g1g2k5o — round-15 verified variant (128px tile, 512 thr / 8 waves),
// with K/V staging now a vectorized copy of pre-packed KclsP/VclsP.
// Classes 19..31 in KclsP/VclsP hold benign junk (finite 0xAAAA): K-junk rows
// are discarded before softmax; V-junk is multiplied by P=0. Same as before.
// ---------------------------------------------------------------------------
__global__ __launch_bounds__(512, 1) void g1g2k5o(
    const unsigned short* __restrict__ xT, const unsigned short* __restrict__ W1,
    const float* __restrict__ g1, const float* __restrict__ b1,
    const unsigned short* __restrict__ W2, const float* __restrict__ g2,
    const float* __restrict__ b2, const unsigned short* __restrict__ KclsP,
    const unsigned short* __restrict__ VclsP,
    const unsigned int* __restrict__ cnt_part,
    const unsigned short* __restrict__ Wo, const float* __restrict__ og,
    const float* __restrict__ ob, float* __restrict__ out) {
  __shared__ __align__(16) char RC[49152];  // As+Bs dbuf | simT+Pl | WoBuf
  __shared__ __align__(16) unsigned short Q1f[8][4096];      // q1 -> q2 -> ctx
  __shared__ __align__(16) unsigned short Kl2[32 * 32 * 8];  // 16 KB
  __shared__ __align__(16) unsigned short Vl2[4 * 256 * 8];  // 16 KB
  __shared__ float cntl[NK];
  unsigned short* As = (unsigned short*)RC;            // [2][128*32]
  unsigned short* Bs = (unsigned short*)(RC + 16384);  // [2][256*32]
  float* simT = (float*)RC;                            // phase-2 overlay
  unsigned short* Pl = (unsigned short*)(RC + 16896);
  unsigned short* WoBuf = (unsigned short*)RC;         // stage-5 overlay, 32 KB

  int b = blockIdx.y;
  int p0 = blockIdx.x * 128;
  int tid = threadIdx.x;
  int l = tid & 63, w = tid >> 6;  // 8 waves
  int wp = w & 3, wm = w >> 2;     // GEMM decomposition
  const unsigned short* xTb = xT + ((size_t)b * HW + p0) * CIN;

  // K/V staging: vectorized copy of pre-packed layouts (verified formulas)
  for (int i = tid; i < 1024; i += 512) {
    *(short8*)&Kl2[i * 8] = *(const short8*)&KclsP[(size_t)b * 8192 + i * 8];
    *(short8*)&Vl2[i * 8] = *(const short8*)&VclsP[(size_t)b * 8192 + i * 8];
  }
  if (tid < NK) {
    unsigned int s = 0u;
#pragma unroll
    for (int j = 0; j < 16; ++j) s += cnt_part[(b * 16 + j) * 32 + tid];
    cntl[tid] = (float)s;
  }

  f32x4 acc[2][8];

  // ---- stage 1a: q1, K=512 ----
  auto STAGE_A1 = [&](int buf, int t) {
    int k0 = t * 32;
    int e = tid * 8;
    int rl = e >> 5, sl = (e >> 3) & 3;
    gload16(xTb + (size_t)rl * CIN + k0 + 8 * (sl ^ ((rl >> 1) & 3)),
            &As[buf * 4096 + w * 512]);
  };
  auto STAGE_B1 = [&](int buf, int t) {
    int k0 = t * 32;
#pragma unroll
    for (int q = 0; q < 2; ++q) {
      int e = q * 4096 + tid * 8;
      int rl = e >> 5, sl = (e >> 3) & 3;
      gload16(W1 + (size_t)rl * CIN + k0 + 8 * (sl ^ ((rl >> 1) & 3)),
              &Bs[buf * 8192 + q * 4096 + w * 512]);
    }
  };
#pragma unroll
  for (int i = 0; i < 2; ++i)
#pragma unroll
    for (int j = 0; j < 8; ++j) acc[i][j] = (f32x4){0.f, 0.f, 0.f, 0.f};
  STAGE_A1(0, 0);
  STAGE_B1(0, 0);
  for (int t = 0; t < 16; ++t) {
    __syncthreads();
    if (t + 1 < 16) { STAGE_A1((t + 1) & 1, t + 1); STAGE_B1((t + 1) & 1, t + 1); }
    int cur = t & 1;
    short8 af[2];
#pragma unroll
    for (int f = 0; f < 2; ++f) {
      int nl = wp * 32 + f * 16 + (l & 15);
      af[f] =
          *(const short8*)&As[cur * 4096 + nl * 32 + 8 * ((l >> 4) ^ ((nl >> 1) & 3))];
    }
#pragma unroll
    for (int mf = 0; mf < 8; ++mf) {
      int ml = wm * 128 + mf * 16 + (l & 15);
      short8 bf =
          *(const short8*)&Bs[cur * 8192 + ml * 32 + 8 * ((l >> 4) ^ ((ml >> 1) & 3))];
      acc[0][mf] =
          __builtin_amdgcn_mfma_f32_16x16x32_bf16(af[0], bf, acc[0][mf], 0, 0, 0);
      acc[1][mf] =
          __builtin_amdgcn_mfma_f32_16x16x32_bf16(af[1], bf, acc[1][mf], 0, 0, 0);
    }
  }
#pragma unroll
  for (int mf = 0; mf < 8; ++mf) {
    int ch = wm * 128 + mf * 16 + (l & 15);
    float gm = g1[ch], bm = b1[ch];
    int tq = ch >> 5, slot = (ch >> 3) & 3, wi = ch & 7;
#pragma unroll
    for (int i = 0; i < 2; ++i) {
#pragma unroll
      for (int r = 0; r < 4; ++r) {
        int p = wp * 32 + i * 16 + (l >> 4) * 4 + r;
        Q1f[tq][p * 32 + 8 * (slot ^ ((p >> 1) & 3)) + wi] =
            f2bf(fmaxf(acc[i][mf][r] * gm + bm, 0.f));
      }
    }
  }

  // ---- stage 1b: q2, K=256, A from Q1f ----
  auto STAGE_B2 = [&](int buf, int t) {
    int k0 = t * 32;
#pragma unroll
    for (int q = 0; q < 2; ++q) {
      int e = q * 4096 + tid * 8;
      int rl = e >> 5, sl = (e >> 3) & 3;
      gload16(W2 + (size_t)rl * CTC + k0 + 8 * (sl ^ ((rl >> 1) & 3)),
              &Bs[buf * 8192 + q * 4096 + w * 512]);
    }
  };
#pragma unroll
  for (int i = 0; i < 2; ++i)
#pragma unroll
    for (int j = 0; j < 8; ++j) acc[i][j] = (f32x4){0.f, 0.f, 0.f, 0.f};
  STAGE_B2(0, 0);
  for (int t = 0; t < 8; ++t) {
    __syncthreads();  // Q1f visible (t=0); Bs[cur] staged; prev Bs reads done
    if (t + 1 < 8) STAGE_B2((t + 1) & 1, t + 1);
    int cur = t & 1;
    short8 af[2];
#pragma unroll
    for (int f = 0; f < 2; ++f) {
      int nl = wp * 32 + f * 16 + (l & 15);
      af[f] = *(const short8*)&Q1f[t][nl * 32 + 8 * ((l >> 4) ^ ((nl >> 1) & 3))];
    }
#pragma unroll
    for (int mf = 0; mf < 8; ++mf) {
      int ml = wm * 128 + mf * 16 + (l & 15);
      short8 bf =
          *(const short8*)&Bs[cur * 8192 + ml * 32 + 8 * ((l >> 4) ^ ((ml >> 1) & 3))];
      acc[0][mf] =
          __builtin_amdgcn_mfma_f32_16x16x32_bf16(af[0], bf, acc[0][mf], 0, 0, 0);
      acc[1][mf] =
          __builtin_amdgcn_mfma_f32_16x16x32_bf16(af[1], bf, acc[1][mf], 0, 0, 0);
    }
  }
  __syncthreads();  // all waves' Q1f reads done before overlay write
#pragma unroll
  for (int mf = 0; mf < 8; ++mf) {
    int ch = wm * 128 + mf * 16 + (l & 15);
    float gm = g2[ch], bm = b2[ch];
    int tq = ch >> 5, slot = (ch >> 3) & 3, wi = ch & 7;
#pragma unroll
    for (int i = 0; i < 2; ++i) {
#pragma unroll
      for (int r = 0; r < 4; ++r) {
        int p = wp * 32 + i * 16 + (l >> 4) * 4 + r;
        Q1f[tq][p * 32 + 8 * (slot ^ ((p >> 1) & 3)) + wi] =
            f2bf(fmaxf(acc[i][mf][r] * gm + bm, 0.f));
      }
    }
  }
  __syncthreads();  // Qf (=q2) complete

  // ---- stage 2: sim = q2 . Kcls (8 waves x 16 pixels) ----
  f32x4 a2[2];
  a2[0] = (f32x4){0.f, 0.f, 0.f, 0.f};
  a2[1] = (f32x4){0.f, 0.f, 0.f, 0.f};
  for (int t = 0; t < 8; ++t) {
    int nl = w * 16 + (l & 15);
    short8 aq =
        *(const short8*)&Q1f[t][nl * 32 + 8 * ((l >> 4) ^ ((nl >> 1) & 3))];
    int s = t * 4 + (l >> 4);
#pragma unroll
    for (int j = 0; j < 2; ++j) {
      int ml = j * 16 + (l & 15);
      short8 bk = *(const short8*)&Kl2[(s * 32 + ml) * 8];
      a2[j] = __builtin_amdgcn_mfma_f32_16x16x32_bf16(aq, bk, a2[j], 0, 0, 0);
    }
  }
  __syncthreads();  // RC (As/Bs) dead -> becomes simT/Pl
#pragma unroll
  for (int j = 0; j < 2; ++j) {
    int m = j * 16 + (l & 15);
    if (m < NK) {
#pragma unroll
      for (int r = 0; r < 4; ++r) {
        int p = w * 16 + (l >> 4) * 4 + r;
        simT[p * 33 + m] = a2[j][r];
      }
    }
  }
  __syncthreads();
  if (tid < 128) {
    float sims[NK];
#pragma unroll
    for (int k = 0; k < NK; ++k) sims[k] = simT[tid * 33 + k] * 0.0625f;
    float m = -1e30f;
#pragma unroll
    for (int k = 0; k < NK; ++k)
      if (cntl[k] > 0.f) m = fmaxf(m, sims[k]);
    float d = 0.f;
#pragma unroll
    for (int k = 0; k < NK; ++k) {
      float e = (cntl[k] > 0.f) ? expf(sims[k] - m) : 0.f;
      sims[k] = cntl[k] * e;
      d += sims[k];
    }
    float inv = 1.f / d;
#pragma unroll
    for (int s = 0; s < 4; ++s) {
      union { short8 v; unsigned short u8[8]; } pk;
#pragma unroll
      for (int j = 0; j < 8; ++j) {
        int k = s * 8 + j;
        pk.u8[j] = (k < NK) ? f2bf(sims[k] * inv) : (unsigned short)0;
      }
      *(short8*)&Pl[(s * 128 + tid) * 8] = pk.v;
    }
  }
  __syncthreads();
  // ---- stage 4: PV -> ctx bf16 -> Q1f (verified chunk-swizzle write) ----
  short8 ap;
  {
    int nl = w * 16 + (l & 15);
    ap = *(const short8*)&Pl[((l >> 4) * 128 + nl) * 8];
  }
#pragma unroll
  for (int mc = 0; mc < 4; ++mc) {
#pragma unroll
    for (int mf = 0; mf < 4; ++mf) {
      int ml = mc * 64 + mf * 16 + (l & 15);
      short8 bv = *(const short8*)&Vl2[((l >> 4) * 256 + ml) * 8];
      f32x4 z = {0.f, 0.f, 0.f, 0.f};
      f32x4 o = __builtin_amdgcn_mfma_f32_16x16x32_bf16(ap, bv, z, 0, 0, 0);
      int tq = ml >> 5, slot = (ml >> 3) & 3, wi = ml & 7;
#pragma unroll
      for (int r = 0; r < 4; ++r) {
        int p = w * 16 + (l >> 4) * 4 + r;
        Q1f[tq][p * 32 + 8 * (slot ^ ((p >> 1) & 3)) + wi] = f2bf(o[r]);
      }
    }
  }

  // ---- stage 5: out = relu(og*(Wo . ctx)+ob), K=256, M=512 ----
  f32x4 a5[2][16];
#pragma unroll
  for (int i = 0; i < 2; ++i)
#pragma unroll
    for (int j = 0; j < 16; ++j) a5[i][j] = (f32x4){0.f, 0.f, 0.f, 0.f};
  for (int t = 0; t < 8; ++t) {
    __syncthreads();  // t=0: PV's Q1f writes + Pl reads complete; else: prev
                      // WoBuf MFMA reads complete
#pragma unroll
    for (int q = 0; q < 4; ++q) {  // 512 rows x 32 k = 32 KB
      int e = q * 4096 + tid * 8;
      int rl = e >> 5, sl = (e >> 3) & 3;
      gload16(Wo + (size_t)rl * CTC + t * 32 + 8 * (sl ^ ((rl >> 1) & 3)),
              &WoBuf[q * 4096 + w * 512]);
    }
    __syncthreads();  // staging drained + visible
    short8 af[2];
#pragma unroll
    for (int f = 0; f < 2; ++f) {
      int nl = wp * 32 + f * 16 + (l & 15);
      af[f] = *(const short8*)&Q1f[t][nl * 32 + 8 * ((l >> 4) ^ ((nl >> 1) & 3))];
    }
#pragma unroll
    for (int mf = 0; mf < 16; ++mf) {
      int ml = wm * 256 + mf * 16 + (l & 15);
      short8 bf =
          *(const short8*)&WoBuf[ml * 32 + 8 * ((l >> 4) ^ ((ml >> 1) & 3))];
      a5[0][mf] =
          __builtin_amdgcn_mfma_f32_16x16x32_bf16(af[0], bf, a5[0][mf], 0, 0, 0);
      a5[1][mf] =
          __builtin_amdgcn_mfma_f32_16x16x32_bf16(af[1], bf, a5[1][mf], 0, 0, 0);
    }
  }
  // epilogue: f32 float4 stores (same mapping as gemm_mfma outmode 0)
  float* outb = out + (size_t)b * CIN * HW;
#pragma unroll
  for (int mf = 0; mf < 16; ++mf) {
    int co = wm * 256 + mf * 16 + (l & 15);
    float gm = og[co], bm = ob[co];
#pragma unroll
    for (int i = 0; i < 2; ++i) {
      int n = p0 + wp * 32 + i * 16 + (l >> 4) * 4;
      float4 o;
      o.x = fmaxf(a5[i][mf][0] * gm + bm, 0.f);
      o.y = fmaxf(a5[i][mf][1] * gm + bm, 0.f);
      o.z = fmaxf(a5[i][mf][2] * gm + bm, 0.f);
      o.w = fmaxf(a5[i][mf][3] * gm + bm, 0.f);
      *(float4*)&outb[(size_t)co * HW + n] = o;
    }
  }
}

// ---------------------------------------------------------------------------
extern "C" void kernel_launch(void* const* d_in, const int* in_sizes, int n_in,
                              void* d_out, int out_size, void* d_ws, size_t ws_size,
                              hipStream_t stream) {
  const float* x = (const float*)d_in[0];
  const float* preds = (const float*)d_in[1];
  const float* q_w1 = (const float*)d_in[3];
  const float* q_g1 = (const float*)d_in[4];
  const float* q_b1 = (const float*)d_in[5];
  const float* q_w2 = (const float*)d_in[6];
  const float* q_g2 = (const float*)d_in[7];
  const float* q_b2 = (const float*)d_in[8];
  const float* k_w1 = (const float*)d_in[9];
  const float* k_g1 = (const float*)d_in[10];
  const float* k_b1 = (const float*)d_in[11];
  const float* k_w2 = (const float*)d_in[12];
  const float* k_g2 = (const float*)d_in[13];
  const float* k_b2 = (const float*)d_in[14];
  const float* v_w = (const float*)d_in[15];
  const float* v_g = (const float*)d_in[16];
  const float* v_b = (const float*)d_in[17];
  const float* o_w = (const float*)d_in[18];
  const float* o_g = (const float*)d_in[19];
  const float* o_b = (const float*)d_in[20];
  float* out = (float*)d_out;

  char* base = (char*)d_ws;
  unsigned short* xT = (unsigned short*)base;               // 33,554,432 B
  char* f32r = base + 33554432;
  float* cls_feat = (float*)f32r;                            // 311,296 B
  unsigned short* KclsP = (unsigned short*)(f32r + 311296);  // 131,072 B
  unsigned short* VclsP = (unsigned short*)(f32r + 442368);  // 131,072 B
  unsigned short* wb1 = (unsigned short*)(f32r + 573440);    // 262,144 B
  unsigned short* wb2 = (unsigned short*)(f32r + 835584);    // 131,072 B
  unsigned short* wbo = (unsigned short*)(f32r + 966656);    // 262,144 B
  float* h1g = (float*)(f32r + 1228800);                     // 155,648 B
  float* bestg = (float*)(f32r + 1384448);                   // 131,072 B
  int* clsg = (int*)(f32r + 1515520);                        // 131,072 B
  unsigned int* Mu_part = (unsigned int*)(f32r + 1646592);   // 16,384 B
  unsigned int* cnt_part = (unsigned int*)(f32r + 1662976);  // 16,384 B
  float* Zf_part = (float*)(f32r + 1679360);                 // 16,384 B

  wk1a<<<448, 256, 0, stream>>>(q_w1, q_w2, o_w, wb1, wb2, wbo,
                                (uint4*)cls_feat, preds, bestg, clsg, Mu_part,
                                cnt_part);
  k1b<<<dim3(16, NB), 256, 0, stream>>>(bestg, clsg, Mu_part, Zf_part);
  xk2<<<dim3(8, 8, NB), 256, 0, stream>>>(x, bestg, clsg, Zf_part, xT,
                                          cls_feat);
  k3a<<<dim3(4, NB * NK), 256, 0, stream>>>(cls_feat, k_w1, k_g1, k_b1, v_w,
                                            v_g, v_b, h1g, VclsP);
  k3b<<<dim3(4, NB * NK), 256, 0, stream>>>(h1g, k_w2, k_g2, k_b2, KclsP);
  g1g2k5o<<<dim3(HW / 128, NB), 512, 0, stream>>>(xT, wb1, q_g1, q_b1, wb2,
                                                  q_g2, q_b2, KclsP, VclsP,
                                                  cnt_part, wbo, o_g, o_b,
                                                  out);
}

// Round 18
// 111.143 us; speedup vs baseline: 1.0423x; 1.0140x over previous
//
#include <hip/hip_runtime.h>
#include <math.h>

#define HW 4096
#define NB 8
#define NK 19
#define CIN 512
#define CTC 256

typedef __attribute__((ext_vector_type(8))) short short8;
typedef __attribute__((ext_vector_type(4))) float f32x4;

__device__ inline unsigned short f2bf(float x) {
  unsigned u = __float_as_uint(x);
  return (unsigned short)((u + 0x7fffu + ((u >> 16) & 1u)) >> 16);  // RNE
}
__device__ inline float bf2f(unsigned short h) {
  return __uint_as_float(((unsigned)h) << 16);
}
__device__ inline void gload16(const void* g, void* l) {
  __builtin_amdgcn_global_load_lds(
      (const __attribute__((address_space(1))) void*)g,
      (__attribute__((address_space(3))) void*)l, 16, 0, 0);
}

// ---------------------------------------------------------------------------
// wk1a (verified round 12): weight convert + cls_feat zero + k1a partials.
// ---------------------------------------------------------------------------
__global__ __launch_bounds__(256) void wk1a(
    const float* __restrict__ w1, const float* __restrict__ w2,
    const float* __restrict__ wo, unsigned short* __restrict__ wb1,
    unsigned short* __restrict__ wb2, unsigned short* __restrict__ wbo,
    uint4* __restrict__ cls_feat_z, const float* __restrict__ preds,
    float* __restrict__ bestg, int* __restrict__ clsg,
    unsigned int* __restrict__ Mu_part, unsigned int* __restrict__ cnt_part) {
  __shared__ unsigned int Mw[NK];
  __shared__ unsigned int Cw[NK];
  int bx = blockIdx.x;
  int tid = threadIdx.x;
  if (bx < 320) {
    int gid = bx * 256 + tid;
    int i = gid * 4;  // [0, 327680)
    const float* src;
    unsigned short* dst;
    int off;
    if (i < 131072) { src = w1; dst = wb1; off = i; }
    else if (i < 196608) { src = w2; dst = wb2; off = i - 131072; }
    else { src = wo; dst = wbo; off = i - 196608; }
    float4 v = *(const float4*)(src + off);
    dst[off + 0] = f2bf(v.x);
    dst[off + 1] = f2bf(v.y);
    dst[off + 2] = f2bf(v.z);
    dst[off + 3] = f2bf(v.w);
    uint4 z = {0u, 0u, 0u, 0u};
    for (int j = gid; j < 19456; j += 81920) cls_feat_z[j] = z;
  } else {
    int bq = bx - 320;
    int b = bq >> 4, pblk = bq & 15;
    if (tid < NK) { Mw[tid] = 0u; Cw[tid] = 0u; }
    __syncthreads();
    int p = pblk * 256 + tid;
    const float* pb = preds + (size_t)b * NK * HW;
    float best = pb[p];
    int bi = 0;
#pragma unroll
    for (int k = 1; k < NK; ++k) {
      float v = pb[k * HW + p];
      if (v > best) { best = v; bi = k; }  // strict > = jnp.argmax first-index
    }
    bestg[b * HW + p] = best;
    clsg[b * HW + p] = bi;
    unsigned fb = __float_as_uint(best);
    unsigned key = (fb & 0x80000000u) ? ~fb : (fb | 0x80000000u);
    atomicMax(&Mw[bi], key);
    atomicAdd(&Cw[bi], 1u);
    __syncthreads();
    if (tid < 32) {
      Mu_part[(b * 16 + pblk) * 32 + tid] = (tid < NK) ? Mw[tid] : 0u;
      cnt_part[(b * 16 + pblk) * 32 + tid] = (tid < NK) ? Cw[tid] : 0u;
    }
  }
}

// ---------------------------------------------------------------------------
// k1b (verified round 12).
// ---------------------------------------------------------------------------
__global__ __launch_bounds__(256) void k1b(
    float* __restrict__ bestg, const int* __restrict__ clsg,
    const unsigned int* __restrict__ Mu_part, float* __restrict__ Zf_part) {
  int b = blockIdx.y, pblk = blockIdx.x;
  int tid = threadIdx.x;
  __shared__ float Mf[NK];
  __shared__ float Zw[NK];
  if (tid < NK) {
    unsigned key = 0u;
#pragma unroll
    for (int j = 0; j < 16; ++j) {
      unsigned v = Mu_part[(b * 16 + j) * 32 + tid];
      key = (v > key) ? v : key;
    }
    float m = -1e30f;
    if (key) {
      unsigned fb = (key & 0x80000000u) ? (key & 0x7fffffffu) : ~key;
      m = __uint_as_float(fb);
    }
    Mf[tid] = m;
    Zw[tid] = 0.f;
  }
  __syncthreads();
  int p = pblk * 256 + tid;
  int c = clsg[b * HW + p];
  float e = expf(bestg[b * HW + p] - Mf[c]);
  bestg[b * HW + p] = e;
  atomicAdd(&Zw[c], e);
  __syncthreads();
  if (tid < 32) Zf_part[(b * 16 + pblk) * 32 + tid] = (tid < NK) ? Zw[tid] : 0.f;
}

// ---------------------------------------------------------------------------
// FUSED xk2 (verified round 12).
// ---------------------------------------------------------------------------
__global__ __launch_bounds__(256) void xk2(
    const float* __restrict__ x, const float* __restrict__ eg,
    const int* __restrict__ clsg, const float* __restrict__ Zf_part,
    unsigned short* __restrict__ xT, float* __restrict__ cls_feat) {
  __shared__ float tile[64][65];
  __shared__ unsigned short Bs[32 * 516];
  __shared__ float Zl[NK];
  int b = blockIdx.z, c0 = blockIdx.y * 64, pbase = blockIdx.x * 512;
  int tid = threadIdx.x;
  int l = tid & 63, w = tid >> 6;
  if (tid < NK) {
    float s = 0.f;
#pragma unroll
    for (int j = 0; j < 16; ++j) s += Zf_part[(b * 16 + j) * 32 + tid];
    Zl[tid] = s;
  }
  {
    uint4 z = {0u, 0u, 0u, 0u};
    for (int i = tid; i < 2064; i += 256) ((uint4*)Bs)[i] = z;
  }
  __syncthreads();
  for (int i = tid; i < 512; i += 256) {
    int c = clsg[b * HW + pbase + i];
    Bs[c * 516 + i] = f2bf(eg[b * HW + pbase + i] / Zl[c]);
  }
  f32x4 acc[2];
  acc[0] = (f32x4){0.f, 0.f, 0.f, 0.f};
  acc[1] = (f32x4){0.f, 0.f, 0.f, 0.f};
  int cbase = w * 16;
  for (int s = 0; s < 8; ++s) {
    int ps = pbase + s * 64;
    __syncthreads();
#pragma unroll
    for (int r = 0; r < 4; ++r) {
      int cl = r * 16 + (tid >> 4);
      int pl = (tid & 15) * 4;
      float4 v = *(const float4*)&x[((size_t)b * CIN + c0 + cl) * HW + ps + pl];
      tile[cl][pl + 0] = v.x;
      tile[cl][pl + 1] = v.y;
      tile[cl][pl + 2] = v.z;
      tile[cl][pl + 3] = v.w;
    }
    __syncthreads();
#pragma unroll
    for (int j = 0; j < 16; ++j) {
      int ploc = j * 4 + w;
      xT[((size_t)b * HW + ps + ploc) * CIN + c0 + l] = f2bf(tile[l][ploc]);
    }
#pragma unroll
    for (int ch = 0; ch < 2; ++ch) {
      int pt = ch * 32 + (l >> 4) * 8;
      union { short8 v; unsigned short u[8]; } af;
      const float* tp = &tile[cbase + (l & 15)][pt];
#pragma unroll
      for (int j = 0; j < 8; ++j) af.u[j] = f2bf(tp[j]);
      int pg = s * 64 + pt;
#pragma unroll
      for (int mf = 0; mf < 2; ++mf) {
        short8 bf = *(const short8*)&Bs[(mf * 16 + (l & 15)) * 516 + pg];
        acc[mf] =
            __builtin_amdgcn_mfma_f32_16x16x32_bf16(af.v, bf, acc[mf], 0, 0, 0);
      }
    }
  }
#pragma unroll
  for (int mf = 0; mf < 2; ++mf) {
    int k = mf * 16 + (l & 15);
    if (k < NK) {
#pragma unroll
      for (int r = 0; r < 4; ++r) {
        int c = c0 + cbase + (l >> 4) * 4 + r;
        atomicAdd(&cls_feat[((size_t)b * NK + k) * CIN + c], acc[mf][r]);
      }
    }
  }
}

// ---------------------------------------------------------------------------
// K3a (verified round 17): h1 + VclsP pre-packed bf16 (Vl2 slot-major).
// ---------------------------------------------------------------------------
__global__ __launch_bounds__(256) void k3a(
    const float* __restrict__ cls_feat, const float* __restrict__ kw1,
    const float* __restrict__ kg1, const float* __restrict__ kb1,
    const float* __restrict__ vw, const float* __restrict__ vg,
    const float* __restrict__ vb, float* __restrict__ h1g,
    unsigned short* __restrict__ VclsP) {
  int bk = blockIdx.y;
  int b = bk / NK, kc = bk % NK;
  int q = blockIdx.x;
  __shared__ float cf[CIN];
  int tid = threadIdx.x;
  const float* row = cls_feat + (size_t)bk * CIN;
  for (int i = tid; i < CIN; i += 256) cf[i] = row[i];
  __syncthreads();
  int o = tid >> 1, half = tid & 1;
  int col = q * 64 + (o & 63);
  const float* w =
      (o < 64) ? &kw1[(size_t)col * CIN] : &vw[(size_t)col * CIN];
  int base = half * 256;
  float acc[4] = {0.f, 0.f, 0.f, 0.f};
#pragma unroll 8
  for (int i = 0; i < 64; ++i) {
    float4 w4 = *(const float4*)&w[base + i * 4];
    const float* c4 = &cf[base + i * 4];
    acc[i & 3] += w4.x * c4[0] + w4.y * c4[1] + w4.z * c4[2] + w4.w * c4[3];
  }
  float s = (acc[0] + acc[1]) + (acc[2] + acc[3]);
  s += __shfl_xor(s, 1);
  if (half == 0) {
    if (o < 64) {
      h1g[(size_t)bk * CTC + col] = fmaxf(s * kg1[col] + kb1[col], 0.f);
    } else {
      VclsP[(size_t)b * 8192 + ((kc >> 3) * 256 + col) * 8 + (kc & 7)] =
          f2bf(fmaxf(s * vg[col] + vb[col], 0.f));
    }
  }
}

// ---------------------------------------------------------------------------
// K3b (verified round 17): KclsP pre-packed bf16 (Kl2 slot-major).
// ---------------------------------------------------------------------------
__global__ __launch_bounds__(256) void k3b(
    const float* __restrict__ h1g, const float* __restrict__ kw2,
    const float* __restrict__ kg2, const float* __restrict__ kb2,
    unsigned short* __restrict__ KclsP) {
  int bk = blockIdx.y;
  int b = bk / NK, kc = bk % NK;
  int q = blockIdx.x;
  __shared__ float h1[CTC];
  int tid = threadIdx.x;
  const float* row = h1g + (size_t)bk * CTC;
  if (tid < CTC) h1[tid] = row[tid];
  __syncthreads();
  int o = tid >> 2, part = tid & 3;
  int col = q * 64 + o;
  const float* w = &kw2[(size_t)col * CTC + part * 64];
  const float* c = &h1[part * 64];
  float acc[4] = {0.f, 0.f, 0.f, 0.f};
#pragma unroll
  for (int i = 0; i < 16; ++i) {
    float4 w4 = *(const float4*)&w[i * 4];
    acc[i & 3] += w4.x * c[i * 4] + w4.y * c[i * 4 + 1] + w4.z * c[i * 4 + 2] +
                  w4.w * c[i * 4 + 3];
  }
  float s = (acc[0] + acc[1]) + (acc[2] + acc[3]);
  s += __shfl_xor(s, 1);
  s += __shfl_xor(s, 2);
  if (part == 0)
    KclsP[(size_t)b * 8192 + ((col >> 3) * 32 + kc) * 8 + (col & 7)] =
        f2bf(fmaxf(s * kg2[col] + kb2[col], 0.f));
}

// ---------------------------------------------------------------------------
// FUSED g1g2k5o — round-17 verified kernel with stage 5 restructured to the
// round-16-verified halved/double-buffered form: M in two 256-row halves,
// WoBuf dbuf 2x16KB, one barrier per K-step (prefetch t+1 before compute t),
// half-0 stores overlap half-1's first prefetch. All else byte-identical.
// ---------------------------------------------------------------------------
__global__ __launch_bounds__(512, 1) void g1g2k5o(
    const unsigned short* __restrict__ xT, const unsigned short* __restrict__ W1,
    const float* __restrict__ g1, const float* __restrict__ b1,
    const unsigned short* __restrict__ W2, const float* __restrict__ g2,
    const float* __restrict__ b2, const unsigned short* __restrict__ KclsP,
    const unsigned short* __restrict__ VclsP,
    const unsigned int* __restrict__ cnt_part,
    const unsigned short* __restrict__ Wo, const float* __restrict__ og,
    const float* __restrict__ ob, float* __restrict__ out) {
  __shared__ __align__(16) char RC[49152];  // As+Bs dbuf | simT+Pl | WoBuf dbuf
  __shared__ __align__(16) unsigned short Q1f[8][4096];      // q1 -> q2 -> ctx
  __shared__ __align__(16) unsigned short Kl2[32 * 32 * 8];  // 16 KB
  __shared__ __align__(16) unsigned short Vl2[4 * 256 * 8];  // 16 KB
  __shared__ float cntl[NK];
  unsigned short* As = (unsigned short*)RC;            // [2][128*32]
  unsigned short* Bs = (unsigned short*)(RC + 16384);  // [2][256*32]
  float* simT = (float*)RC;                            // phase-2 overlay
  unsigned short* Pl = (unsigned short*)(RC + 16896);
  unsigned short* WoBuf = (unsigned short*)RC;         // stage-5: [2][256*32]

  int b = blockIdx.y;
  int p0 = blockIdx.x * 128;
  int tid = threadIdx.x;
  int l = tid & 63, w = tid >> 6;  // 8 waves
  int wp = w & 3, wm = w >> 2;     // GEMM decomposition
  const unsigned short* xTb = xT + ((size_t)b * HW + p0) * CIN;

  // K/V staging: vectorized copy of pre-packed layouts (verified round 17)
  for (int i = tid; i < 1024; i += 512) {
    *(short8*)&Kl2[i * 8] = *(const short8*)&KclsP[(size_t)b * 8192 + i * 8];
    *(short8*)&Vl2[i * 8] = *(const short8*)&VclsP[(size_t)b * 8192 + i * 8];
  }
  if (tid < NK) {
    unsigned int s = 0u;
#pragma unroll
    for (int j = 0; j < 16; ++j) s += cnt_part[(b * 16 + j) * 32 + tid];
    cntl[tid] = (float)s;
  }

  f32x4 acc[2][8];

  // ---- stage 1a: q1, K=512 ----
  auto STAGE_A1 = [&](int buf, int t) {
    int k0 = t * 32;
    int e = tid * 8;
    int rl = e >> 5, sl = (e >> 3) & 3;
    gload16(xTb + (size_t)rl * CIN + k0 + 8 * (sl ^ ((rl >> 1) & 3)),
            &As[buf * 4096 + w * 512]);
  };
  auto STAGE_B1 = [&](int buf, int t) {
    int k0 = t * 32;
#pragma unroll
    for (int q = 0; q < 2; ++q) {
      int e = q * 4096 + tid * 8;
      int rl = e >> 5, sl = (e >> 3) & 3;
      gload16(W1 + (size_t)rl * CIN + k0 + 8 * (sl ^ ((rl >> 1) & 3)),
              &Bs[buf * 8192 + q * 4096 + w * 512]);
    }
  };
#pragma unroll
  for (int i = 0; i < 2; ++i)
#pragma unroll
    for (int j = 0; j < 8; ++j) acc[i][j] = (f32x4){0.f, 0.f, 0.f, 0.f};
  STAGE_A1(0, 0);
  STAGE_B1(0, 0);
  for (int t = 0; t < 16; ++t) {
    __syncthreads();
    if (t + 1 < 16) { STAGE_A1((t + 1) & 1, t + 1); STAGE_B1((t + 1) & 1, t + 1); }
    int cur = t & 1;
    short8 af[2];
#pragma unroll
    for (int f = 0; f < 2; ++f) {
      int nl = wp * 32 + f * 16 + (l & 15);
      af[f] =
          *(const short8*)&As[cur * 4096 + nl * 32 + 8 * ((l >> 4) ^ ((nl >> 1) & 3))];
    }
#pragma unroll
    for (int mf = 0; mf < 8; ++mf) {
      int ml = wm * 128 + mf * 16 + (l & 15);
      short8 bf =
          *(const short8*)&Bs[cur * 8192 + ml * 32 + 8 * ((l >> 4) ^ ((ml >> 1) & 3))];
      acc[0][mf] =
          __builtin_amdgcn_mfma_f32_16x16x32_bf16(af[0], bf, acc[0][mf], 0, 0, 0);
      acc[1][mf] =
          __builtin_amdgcn_mfma_f32_16x16x32_bf16(af[1], bf, acc[1][mf], 0, 0, 0);
    }
  }
#pragma unroll
  for (int mf = 0; mf < 8; ++mf) {
    int ch = wm * 128 + mf * 16 + (l & 15);
    float gm = g1[ch], bm = b1[ch];
    int tq = ch >> 5, slot = (ch >> 3) & 3, wi = ch & 7;
#pragma unroll
    for (int i = 0; i < 2; ++i) {
#pragma unroll
      for (int r = 0; r < 4; ++r) {
        int p = wp * 32 + i * 16 + (l >> 4) * 4 + r;
        Q1f[tq][p * 32 + 8 * (slot ^ ((p >> 1) & 3)) + wi] =
            f2bf(fmaxf(acc[i][mf][r] * gm + bm, 0.f));
      }
    }
  }

  // ---- stage 1b: q2, K=256, A from Q1f ----
  auto STAGE_B2 = [&](int buf, int t) {
    int k0 = t * 32;
#pragma unroll
    for (int q = 0; q < 2; ++q) {
      int e = q * 4096 + tid * 8;
      int rl = e >> 5, sl = (e >> 3) & 3;
      gload16(W2 + (size_t)rl * CTC + k0 + 8 * (sl ^ ((rl >> 1) & 3)),
              &Bs[buf * 8192 + q * 4096 + w * 512]);
    }
  };
#pragma unroll
  for (int i = 0; i < 2; ++i)
#pragma unroll
    for (int j = 0; j < 8; ++j) acc[i][j] = (f32x4){0.f, 0.f, 0.f, 0.f};
  STAGE_B2(0, 0);
  for (int t = 0; t < 8; ++t) {
    __syncthreads();  // Q1f visible (t=0); Bs[cur] staged; prev Bs reads done
    if (t + 1 < 8) STAGE_B2((t + 1) & 1, t + 1);
    int cur = t & 1;
    short8 af[2];
#pragma unroll
    for (int f = 0; f < 2; ++f) {
      int nl = wp * 32 + f * 16 + (l & 15);
      af[f] = *(const short8*)&Q1f[t][nl * 32 + 8 * ((l >> 4) ^ ((nl >> 1) & 3))];
    }
#pragma unroll
    for (int mf = 0; mf < 8; ++mf) {
      int ml = wm * 128 + mf * 16 + (l & 15);
      short8 bf =
          *(const short8*)&Bs[cur * 8192 + ml * 32 + 8 * ((l >> 4) ^ ((ml >> 1) & 3))];
      acc[0][mf] =
          __builtin_amdgcn_mfma_f32_16x16x32_bf16(af[0], bf, acc[0][mf], 0, 0, 0);
      acc[1][mf] =
          __builtin_amdgcn_mfma_f32_16x16x32_bf16(af[1], bf, acc[1][mf], 0, 0, 0);
    }
  }
  __syncthreads();  // all waves' Q1f reads done before overlay write
#pragma unroll
  for (int mf = 0; mf < 8; ++mf) {
    int ch = wm * 128 + mf * 16 + (l & 15);
    float gm = g2[ch], bm = b2[ch];
    int tq = ch >> 5, slot = (ch >> 3) & 3, wi = ch & 7;
#pragma unroll
    for (int i = 0; i < 2; ++i) {
#pragma unroll
      for (int r = 0; r < 4; ++r) {
        int p = wp * 32 + i * 16 + (l >> 4) * 4 + r;
        Q1f[tq][p * 32 + 8 * (slot ^ ((p >> 1) & 3)) + wi] =
            f2bf(fmaxf(acc[i][mf][r] * gm + bm, 0.f));
      }
    }
  }
  __syncthreads();  // Qf (=q2) complete

  // ---- stage 2: sim = q2 . Kcls (8 waves x 16 pixels) ----
  f32x4 a2[2];
  a2[0] = (f32x4){0.f, 0.f, 0.f, 0.f};
  a2[1] = (f32x4){0.f, 0.f, 0.f, 0.f};
  for (int t = 0; t < 8; ++t) {
    int nl = w * 16 + (l & 15);
    short8 aq =
        *(const short8*)&Q1f[t][nl * 32 + 8 * ((l >> 4) ^ ((nl >> 1) & 3))];
    int s = t * 4 + (l >> 4);
#pragma unroll
    for (int j = 0; j < 2; ++j) {
      int ml = j * 16 + (l & 15);
      short8 bk = *(const short8*)&Kl2[(s * 32 + ml) * 8];
      a2[j] = __builtin_amdgcn_mfma_f32_16x16x32_bf16(aq, bk, a2[j], 0, 0, 0);
    }
  }
  __syncthreads();  // RC (As/Bs) dead -> becomes simT/Pl
#pragma unroll
  for (int j = 0; j < 2; ++j) {
    int m = j * 16 + (l & 15);
    if (m < NK) {
#pragma unroll
      for (int r = 0; r < 4; ++r) {
        int p = w * 16 + (l >> 4) * 4 + r;
        simT[p * 33 + m] = a2[j][r];
      }
    }
  }
  __syncthreads();
  if (tid < 128) {
    float sims[NK];
#pragma unroll
    for (int k = 0; k < NK; ++k) sims[k] = simT[tid * 33 + k] * 0.0625f;
    float m = -1e30f;
#pragma unroll
    for (int k = 0; k < NK; ++k)
      if (cntl[k] > 0.f) m = fmaxf(m, sims[k]);
    float d = 0.f;
#pragma unroll
    for (int k = 0; k < NK; ++k) {
      float e = (cntl[k] > 0.f) ? expf(sims[k] - m) : 0.f;
      sims[k] = cntl[k] * e;
      d += sims[k];
    }
    float inv = 1.f / d;
#pragma unroll
    for (int s = 0; s < 4; ++s) {
      union { short8 v; unsigned short u8[8]; } pk;
#pragma unroll
      for (int j = 0; j < 8; ++j) {
        int k = s * 8 + j;
        pk.u8[j] = (k < NK) ? f2bf(sims[k] * inv) : (unsigned short)0;
      }
      *(short8*)&Pl[(s * 128 + tid) * 8] = pk.v;
    }
  }
  __syncthreads();
  // ---- stage 4: PV -> ctx bf16 -> Q1f (verified chunk-swizzle write) ----
  short8 ap;
  {
    int nl = w * 16 + (l & 15);
    ap = *(const short8*)&Pl[((l >> 4) * 128 + nl) * 8];
  }
#pragma unroll
  for (int mc = 0; mc < 4; ++mc) {
#pragma unroll
    for (int mf = 0; mf < 4; ++mf) {
      int ml = mc * 64 + mf * 16 + (l & 15);
      short8 bv = *(const short8*)&Vl2[((l >> 4) * 256 + ml) * 8];
      f32x4 z = {0.f, 0.f, 0.f, 0.f};
      f32x4 o = __builtin_amdgcn_mfma_f32_16x16x32_bf16(ap, bv, z, 0, 0, 0);
      int tq = ml >> 5, slot = (ml >> 3) & 3, wi = ml & 7;
#pragma unroll
      for (int r = 0; r < 4; ++r) {
        int p = w * 16 + (l >> 4) * 4 + r;
        Q1f[tq][p * 32 + 8 * (slot ^ ((p >> 1) & 3)) + wi] = f2bf(o[r]);
      }
    }
  }

  // ---- stage 5: out = relu(og*(Wo.ctx)+ob), K=256, M=512 in 2 halves,
  //      WoBuf dbuf [2][16KB], one barrier/step (round-16-verified shape) ----
  auto STAGE_WO = [&](int hm, int buf, int t) {  // 16 KB: 2 gloads/thread
    int k0 = t * 32;
#pragma unroll
    for (int q = 0; q < 2; ++q) {
      int e = q * 4096 + tid * 8;
      int rl = e >> 5, sl = (e >> 3) & 3;
      gload16(Wo + (size_t)(hm * 256 + rl) * CTC + k0 + 8 * (sl ^ ((rl >> 1) & 3)),
              &WoBuf[buf * 8192 + q * 4096 + w * 512]);
    }
  };
  float* outb = out + (size_t)b * CIN * HW;
  // prologue: WoBuf[0] = RC[0,16K) overlaps only simT (dead after stage-3
  // barrier); Pl (RC+16896..25088) untouched until after first loop barrier.
  STAGE_WO(0, 0, 0);
  for (int hm = 0; hm < 2; ++hm) {
#pragma unroll
    for (int i = 0; i < 2; ++i)
#pragma unroll
      for (int j = 0; j < 8; ++j) acc[i][j] = (f32x4){0.f, 0.f, 0.f, 0.f};
    for (int t = 0; t < 8; ++t) {
      __syncthreads();  // t=0,hm=0: all PV Q1f writes + Pl reads complete;
                        // else: prev WoBuf[cur] reads complete + loads drained
      if (t + 1 < 8) STAGE_WO(hm, (t + 1) & 1, t + 1);
      int cur = t & 1;
      short8 af[2];
#pragma unroll
      for (int f = 0; f < 2; ++f) {
        int nl = wp * 32 + f * 16 + (l & 15);
        af[f] =
            *(const short8*)&Q1f[t][nl * 32 + 8 * ((l >> 4) ^ ((nl >> 1) & 3))];
      }
#pragma unroll
      for (int mf = 0; mf < 8; ++mf) {
        int ml = wm * 128 + mf * 16 + (l & 15);  // row within the 256-half
        short8 bf =
            *(const short8*)&WoBuf[cur * 8192 + ml * 32 + 8 * ((l >> 4) ^ ((ml >> 1) & 3))];
        acc[0][mf] =
            __builtin_amdgcn_mfma_f32_16x16x32_bf16(af[0], bf, acc[0][mf], 0, 0, 0);
        acc[1][mf] =
            __builtin_amdgcn_mfma_f32_16x16x32_bf16(af[1], bf, acc[1][mf], 0, 0, 0);
      }
    }
    // issue next half's first staging into buf0 (all waves done with buf0 at
    // the t=7 barrier) so half-0's stores overlap it
    if (hm == 0) STAGE_WO(1, 0, 0);
    // stores: f32 float4 (same mapping as verified gemm outmode 0)
#pragma unroll
    for (int mf = 0; mf < 8; ++mf) {
      int co = hm * 256 + wm * 128 + mf * 16 + (l & 15);
      float gm = og[co], bm = ob[co];
#pragma unroll
      for (int i = 0; i < 2; ++i) {
        int n = p0 + wp * 32 + i * 16 + (l >> 4) * 4;
        float4 o;
        o.x = fmaxf(acc[i][mf][0] * gm + bm, 0.f);
        o.y = fmaxf(acc[i][mf][1] * gm + bm, 0.f);
        o.z = fmaxf(acc[i][mf][2] * gm + bm, 0.f);
        o.w = fmaxf(acc[i][mf][3] * gm + bm, 0.f);
        *(float4*)&outb[(size_t)co * HW + n] = o;
      }
    }
  }
}

// ---------------------------------------------------------------------------
extern "C" void kernel_launch(void* const* d_in, const int* in_sizes, int n_in,
                              void* d_out, int out_size, void* d_ws, size_t ws_size,
                              hipStream_t stream) {
  const float* x = (const float*)d_in[0];
  const float* preds = (const float*)d_in[1];
  const float* q_w1 = (const float*)d_in[3];
  const float* q_g1 = (const float*)d_in[4];
  const float* q_b1 = (const float*)d_in[5];
  const float* q_w2 = (const float*)d_in[6];
  const float* q_g2 = (const float*)d_in[7];
  const float* q_b2 = (const float*)d_in[8];
  const float* k_w1 = (const float*)d_in[9];
  const float* k_g1 = (const float*)d_in[10];
  const float* k_b1 = (const float*)d_in[11];
  const float* k_w2 = (const float*)d_in[12];
  const float* k_g2 = (const float*)d_in[13];
  const float* k_b2 = (const float*)d_in[14];
  const float* v_w = (const float*)d_in[15];
  const float* v_g = (const float*)d_in[16];
  const float* v_b = (const float*)d_in[17];
  const float* o_w = (const float*)d_in[18];
  const float* o_g = (const float*)d_in[19];
  const float* o_b = (const float*)d_in[20];
  float* out = (float*)d_out;

  char* base = (char*)d_ws;
  unsigned short* xT = (unsigned short*)base;               // 33,554,432 B
  char* f32r = base + 33554432;
  float* cls_feat = (float*)f32r;                            // 311,296 B
  unsigned short* KclsP = (unsigned short*)(f32r + 311296);  // 131,072 B
  unsigned short* VclsP = (unsigned short*)(f32r + 442368);  // 131,072 B
  unsigned short* wb1 = (unsigned short*)(f32r + 573440);    // 262,144 B
  unsigned short* wb2 = (unsigned short*)(f32r + 835584);    // 131,072 B
  unsigned short* wbo = (unsigned short*)(f32r + 966656);    // 262,144 B
  float* h1g = (float*)(f32r + 1228800);                     // 155,648 B
  float* bestg = (float*)(f32r + 1384448);                   // 131,072 B
  int* clsg = (int*)(f32r + 1515520);                        // 131,072 B
  unsigned int* Mu_part = (unsigned int*)(f32r + 1646592);   // 16,384 B
  unsigned int* cnt_part = (unsigned int*)(f32r + 1662976);  // 16,384 B
  float* Zf_part = (float*)(f32r + 1679360);                 // 16,384 B

  wk1a<<<448, 256, 0, stream>>>(q_w1, q_w2, o_w, wb1, wb2, wbo,
                                (uint4*)cls_feat, preds, bestg, clsg, Mu_part,
                                cnt_part);
  k1b<<<dim3(16, NB), 256, 0, stream>>>(bestg, clsg, Mu_part, Zf_part);
  xk2<<<dim3(8, 8, NB), 256, 0, stream>>>(x, bestg, clsg, Zf_part, xT,
                                          cls_feat);
  k3a<<<dim3(4, NB * NK), 256, 0, stream>>>(cls_feat, k_w1, k_g1, k_b1, v_w,
                                            v_g, v_b, h1g, VclsP);
  k3b<<<dim3(4, NB * NK), 256, 0, stream>>>(h1g, k_w2, k_g2, k_b2, KclsP);
  g1g2k5o<<<dim3(HW / 128, NB), 512, 0, stream>>>(xT, wb1, q_g1, q_b1, wb2,
                                                  q_g2, q_b2, KclsP, VclsP,
                                                  cnt_part, wbo, o_g, o_b,
                                                  out);
}

// Round 19
// 110.995 us; speedup vs baseline: 1.0437x; 1.0013x over previous
//
#include <hip/hip_runtime.h>
#include <math.h>

#define HW 4096
#define NB 8
#define NK 19
#define CIN 512
#define CTC 256

typedef __attribute__((ext_vector_type(8))) short short8;
typedef __attribute__((ext_vector_type(4))) float f32x4;

__device__ inline unsigned short f2bf(float x) {
  unsigned u = __float_as_uint(x);
  return (unsigned short)((u + 0x7fffu + ((u >> 16) & 1u)) >> 16);  // RNE
}
__device__ inline float bf2f(unsigned short h) {
  return __uint_as_float(((unsigned)h) << 16);
}
__device__ inline void gload16(const void* g, void* l) {
  __builtin_amdgcn_global_load_lds(
      (const __attribute__((address_space(1))) void*)g,
      (__attribute__((address_space(3))) void*)l, 16, 0, 0);
}

// ---------------------------------------------------------------------------
// wk1a (verified round 12): weight convert + cls_feat zero + k1a partials.
// ---------------------------------------------------------------------------
__global__ __launch_bounds__(256) void wk1a(
    const float* __restrict__ w1, const float* __restrict__ w2,
    const float* __restrict__ wo, unsigned short* __restrict__ wb1,
    unsigned short* __restrict__ wb2, unsigned short* __restrict__ wbo,
    uint4* __restrict__ cls_feat_z, const float* __restrict__ preds,
    float* __restrict__ bestg, int* __restrict__ clsg,
    unsigned int* __restrict__ Mu_part, unsigned int* __restrict__ cnt_part) {
  __shared__ unsigned int Mw[NK];
  __shared__ unsigned int Cw[NK];
  int bx = blockIdx.x;
  int tid = threadIdx.x;
  if (bx < 320) {
    int gid = bx * 256 + tid;
    int i = gid * 4;  // [0, 327680)
    const float* src;
    unsigned short* dst;
    int off;
    if (i < 131072) { src = w1; dst = wb1; off = i; }
    else if (i < 196608) { src = w2; dst = wb2; off = i - 131072; }
    else { src = wo; dst = wbo; off = i - 196608; }
    float4 v = *(const float4*)(src + off);
    dst[off + 0] = f2bf(v.x);
    dst[off + 1] = f2bf(v.y);
    dst[off + 2] = f2bf(v.z);
    dst[off + 3] = f2bf(v.w);
    uint4 z = {0u, 0u, 0u, 0u};
    for (int j = gid; j < 19456; j += 81920) cls_feat_z[j] = z;
  } else {
    int bq = bx - 320;
    int b = bq >> 4, pblk = bq & 15;
    if (tid < NK) { Mw[tid] = 0u; Cw[tid] = 0u; }
    __syncthreads();
    int p = pblk * 256 + tid;
    const float* pb = preds + (size_t)b * NK * HW;
    float best = pb[p];
    int bi = 0;
#pragma unroll
    for (int k = 1; k < NK; ++k) {
      float v = pb[k * HW + p];
      if (v > best) { best = v; bi = k; }  // strict > = jnp.argmax first-index
    }
    bestg[b * HW + p] = best;
    clsg[b * HW + p] = bi;
    unsigned fb = __float_as_uint(best);
    unsigned key = (fb & 0x80000000u) ? ~fb : (fb | 0x80000000u);
    atomicMax(&Mw[bi], key);
    atomicAdd(&Cw[bi], 1u);
    __syncthreads();
    if (tid < 32) {
      Mu_part[(b * 16 + pblk) * 32 + tid] = (tid < NK) ? Mw[tid] : 0u;
      cnt_part[(b * 16 + pblk) * 32 + tid] = (tid < NK) ? Cw[tid] : 0u;
    }
  }
}

// ---------------------------------------------------------------------------
// k1b (verified round 12).
// ---------------------------------------------------------------------------
__global__ __launch_bounds__(256) void k1b(
    float* __restrict__ bestg, const int* __restrict__ clsg,
    const unsigned int* __restrict__ Mu_part, float* __restrict__ Zf_part) {
  int b = blockIdx.y, pblk = blockIdx.x;
  int tid = threadIdx.x;
  __shared__ float Mf[NK];
  __shared__ float Zw[NK];
  if (tid < NK) {
    unsigned key = 0u;
#pragma unroll
    for (int j = 0; j < 16; ++j) {
      unsigned v = Mu_part[(b * 16 + j) * 32 + tid];
      key = (v > key) ? v : key;
    }
    float m = -1e30f;
    if (key) {
      unsigned fb = (key & 0x80000000u) ? (key & 0x7fffffffu) : ~key;
      m = __uint_as_float(fb);
    }
    Mf[tid] = m;
    Zw[tid] = 0.f;
  }
  __syncthreads();
  int p = pblk * 256 + tid;
  int c = clsg[b * HW + p];
  float e = expf(bestg[b * HW + p] - Mf[c]);
  bestg[b * HW + p] = e;
  atomicAdd(&Zw[c], e);
  __syncthreads();
  if (tid < 32) Zf_part[(b * 16 + pblk) * 32 + tid] = (tid < NK) ? Zw[tid] : 0.f;
}

// ---------------------------------------------------------------------------
// FUSED xk2 — round-12-verified body with T14 issue-early/write-late staging:
// sub-tile s+1's global loads are issued before consuming sub-tile s, so HBM
// latency hides under the transpose+MFMA work. Same barriers, same math.
// ---------------------------------------------------------------------------
__global__ __launch_bounds__(256) void xk2(
    const float* __restrict__ x, const float* __restrict__ eg,
    const int* __restrict__ clsg, const float* __restrict__ Zf_part,
    unsigned short* __restrict__ xT, float* __restrict__ cls_feat) {
  __shared__ float tile[64][65];
  __shared__ unsigned short Bs[32 * 516];
  __shared__ float Zl[NK];
  int b = blockIdx.z, c0 = blockIdx.y * 64, pbase = blockIdx.x * 512;
  int tid = threadIdx.x;
  int l = tid & 63, w = tid >> 6;
  if (tid < NK) {
    float s = 0.f;
#pragma unroll
    for (int j = 0; j < 16; ++j) s += Zf_part[(b * 16 + j) * 32 + tid];
    Zl[tid] = s;
  }
  {
    uint4 z = {0u, 0u, 0u, 0u};
    for (int i = tid; i < 2064; i += 256) ((uint4*)Bs)[i] = z;
  }
  __syncthreads();
  for (int i = tid; i < 512; i += 256) {
    int c = clsg[b * HW + pbase + i];
    Bs[c * 516 + i] = f2bf(eg[b * HW + pbase + i] / Zl[c]);
  }
  f32x4 acc[2];
  acc[0] = (f32x4){0.f, 0.f, 0.f, 0.f};
  acc[1] = (f32x4){0.f, 0.f, 0.f, 0.f};
  int cbase = w * 16;
  int clr = (tid >> 4);     // sub-row within 16-row group
  int plr = (tid & 15) * 4; // pixel quad
  float4 rv[4];
#pragma unroll
  for (int r = 0; r < 4; ++r)
    rv[r] = *(const float4*)&x[((size_t)b * CIN + c0 + r * 16 + clr) * HW +
                               pbase + plr];
  for (int s = 0; s < 8; ++s) {
    __syncthreads();  // prev sub-tile consumed; Bs scatter visible (s=0)
#pragma unroll
    for (int r = 0; r < 4; ++r) {
      int cl = r * 16 + clr;
      tile[cl][plr + 0] = rv[r].x;
      tile[cl][plr + 1] = rv[r].y;
      tile[cl][plr + 2] = rv[r].z;
      tile[cl][plr + 3] = rv[r].w;
    }
    float4 rv2[4];
    if (s + 1 < 8) {
      int psn = pbase + (s + 1) * 64;
#pragma unroll
      for (int r = 0; r < 4; ++r)
        rv2[r] = *(const float4*)&x[((size_t)b * CIN + c0 + r * 16 + clr) * HW +
                                    psn + plr];
    }
    __syncthreads();
    int ps = pbase + s * 64;
#pragma unroll
    for (int j = 0; j < 16; ++j) {
      int ploc = j * 4 + w;
      xT[((size_t)b * HW + ps + ploc) * CIN + c0 + l] = f2bf(tile[l][ploc]);
    }
#pragma unroll
    for (int ch = 0; ch < 2; ++ch) {
      int pt = ch * 32 + (l >> 4) * 8;
      union { short8 v; unsigned short u[8]; } af;
      const float* tp = &tile[cbase + (l & 15)][pt];
#pragma unroll
      for (int j = 0; j < 8; ++j) af.u[j] = f2bf(tp[j]);
      int pg = s * 64 + pt;
#pragma unroll
      for (int mf = 0; mf < 2; ++mf) {
        short8 bf = *(const short8*)&Bs[(mf * 16 + (l & 15)) * 516 + pg];
        acc[mf] =
            __builtin_amdgcn_mfma_f32_16x16x32_bf16(af.v, bf, acc[mf], 0, 0, 0);
      }
    }
#pragma unroll
    for (int r = 0; r < 4; ++r) rv[r] = rv2[r];
  }
#pragma unroll
  for (int mf = 0; mf < 2; ++mf) {
    int k = mf * 16 + (l & 15);
    if (k < NK) {
#pragma unroll
      for (int r = 0; r < 4; ++r) {
        int c = c0 + cbase + (l >> 4) * 4 + r;
        atomicAdd(&cls_feat[((size_t)b * NK + k) * CIN + c], acc[mf][r]);
      }
    }
  }
}

// ---------------------------------------------------------------------------
// K3a (verified round 17): h1 + VclsP pre-packed bf16 (Vl2 slot-major).
// ---------------------------------------------------------------------------
__global__ __launch_bounds__(256) void k3a(
    const float* __restrict__ cls_feat, const float* __restrict__ kw1,
    const float* __restrict__ kg1, const float* __restrict__ kb1,
    const float* __restrict__ vw, const float* __restrict__ vg,
    const float* __restrict__ vb, float* __restrict__ h1g,
    unsigned short* __restrict__ VclsP) {
  int bk = blockIdx.y;
  int b = bk / NK, kc = bk % NK;
  int q = blockIdx.x;
  __shared__ float cf[CIN];
  int tid = threadIdx.x;
  const float* row = cls_feat + (size_t)bk * CIN;
  for (int i = tid; i < CIN; i += 256) cf[i] = row[i];
  __syncthreads();
  int o = tid >> 1, half = tid & 1;
  int col = q * 64 + (o & 63);
  const float* w =
      (o < 64) ? &kw1[(size_t)col * CIN] : &vw[(size_t)col * CIN];
  int base = half * 256;
  float acc[4] = {0.f, 0.f, 0.f, 0.f};
#pragma unroll 8
  for (int i = 0; i < 64; ++i) {
    float4 w4 = *(const float4*)&w[base + i * 4];
    const float* c4 = &cf[base + i * 4];
    acc[i & 3] += w4.x * c4[0] + w4.y * c4[1] + w4.z * c4[2] + w4.w * c4[3];
  }
  float s = (acc[0] + acc[1]) + (acc[2] + acc[3]);
  s += __shfl_xor(s, 1);
  if (half == 0) {
    if (o < 64) {
      h1g[(size_t)bk * CTC + col] = fmaxf(s * kg1[col] + kb1[col], 0.f);
    } else {
      VclsP[(size_t)b * 8192 + ((kc >> 3) * 256 + col) * 8 + (kc & 7)] =
          f2bf(fmaxf(s * vg[col] + vb[col], 0.f));
    }
  }
}

// ---------------------------------------------------------------------------
// K3b (verified round 17): KclsP pre-packed bf16 (Kl2 slot-major).
// ---------------------------------------------------------------------------
__global__ __launch_bounds__(256) void k3b(
    const float* __restrict__ h1g, const float* __restrict__ kw2,
    const float* __restrict__ kg2, const float* __restrict__ kb2,
    unsigned short* __restrict__ KclsP) {
  int bk = blockIdx.y;
  int b = bk / NK, kc = bk % NK;
  int q = blockIdx.x;
  __shared__ float h1[CTC];
  int tid = threadIdx.x;
  const float* row = h1g + (size_t)bk * CTC;
  if (tid < CTC) h1[tid] = row[tid];
  __syncthreads();
  int o = tid >> 2, part = tid & 3;
  int col = q * 64 + o;
  const float* w = &kw2[(size_t)col * CTC + part * 64];
  const float* c = &h1[part * 64];
  float acc[4] = {0.f, 0.f, 0.f, 0.f};
#pragma unroll
  for (int i = 0; i < 16; ++i) {
    float4 w4 = *(const float4*)&w[i * 4];
    acc[i & 3] += w4.x * c[i * 4] + w4.y * c[i * 4 + 1] + w4.z * c[i * 4 + 2] +
                  w4.w * c[i * 4 + 3];
  }
  float s = (acc[0] + acc[1]) + (acc[2] + acc[3]);
  s += __shfl_xor(s, 1);
  s += __shfl_xor(s, 2);
  if (part == 0)
    KclsP[(size_t)b * 8192 + ((col >> 3) * 32 + kc) * 8 + (col & 7)] =
        f2bf(fmaxf(s * kg2[col] + kb2[col], 0.f));
}

// ---------------------------------------------------------------------------
// FUSED g1g2k5o (verified round 18): 128px tile / 8 waves; stage-5 halved
// with WoBuf dbuf, one barrier per K-step.
// ---------------------------------------------------------------------------
__global__ __launch_bounds__(512, 1) void g1g2k5o(
    const unsigned short* __restrict__ xT, const unsigned short* __restrict__ W1,
    const float* __restrict__ g1, const float* __restrict__ b1,
    const unsigned short* __restrict__ W2, const float* __restrict__ g2,
    const float* __restrict__ b2, const unsigned short* __restrict__ KclsP,
    const unsigned short* __restrict__ VclsP,
    const unsigned int* __restrict__ cnt_part,
    const unsigned short* __restrict__ Wo, const float* __restrict__ og,
    const float* __restrict__ ob, float* __restrict__ out) {
  __shared__ __align__(16) char RC[49152];  // As+Bs dbuf | simT+Pl | WoBuf dbuf
  __shared__ __align__(16) unsigned short Q1f[8][4096];      // q1 -> q2 -> ctx
  __shared__ __align__(16) unsigned short Kl2[32 * 32 * 8];  // 16 KB
  __shared__ __align__(16) unsigned short Vl2[4 * 256 * 8];  // 16 KB
  __shared__ float cntl[NK];
  unsigned short* As = (unsigned short*)RC;            // [2][128*32]
  unsigned short* Bs = (unsigned short*)(RC + 16384);  // [2][256*32]
  float* simT = (float*)RC;                            // phase-2 overlay
  unsigned short* Pl = (unsigned short*)(RC + 16896);
  unsigned short* WoBuf = (unsigned short*)RC;         // stage-5: [2][256*32]

  int b = blockIdx.y;
  int p0 = blockIdx.x * 128;
  int tid = threadIdx.x;
  int l = tid & 63, w = tid >> 6;  // 8 waves
  int wp = w & 3, wm = w >> 2;     // GEMM decomposition
  const unsigned short* xTb = xT + ((size_t)b * HW + p0) * CIN;

  // K/V staging: vectorized copy of pre-packed layouts (verified round 17)
  for (int i = tid; i < 1024; i += 512) {
    *(short8*)&Kl2[i * 8] = *(const short8*)&KclsP[(size_t)b * 8192 + i * 8];
    *(short8*)&Vl2[i * 8] = *(const short8*)&VclsP[(size_t)b * 8192 + i * 8];
  }
  if (tid < NK) {
    unsigned int s = 0u;
#pragma unroll
    for (int j = 0; j < 16; ++j) s += cnt_part[(b * 16 + j) * 32 + tid];
    cntl[tid] = (float)s;
  }

  f32x4 acc[2][8];

  // ---- stage 1a: q1, K=512 ----
  auto STAGE_A1 = [&](int buf, int t) {
    int k0 = t * 32;
    int e = tid * 8;
    int rl = e >> 5, sl = (e >> 3) & 3;
    gload16(xTb + (size_t)rl * CIN + k0 + 8 * (sl ^ ((rl >> 1) & 3)),
            &As[buf * 4096 + w * 512]);
  };
  auto STAGE_B1 = [&](int buf, int t) {
    int k0 = t * 32;
#pragma unroll
    for (int q = 0; q < 2; ++q) {
      int e = q * 4096 + tid * 8;
      int rl = e >> 5, sl = (e >> 3) & 3;
      gload16(W1 + (size_t)rl * CIN + k0 + 8 * (sl ^ ((rl >> 1) & 3)),
              &Bs[buf * 8192 + q * 4096 + w * 512]);
    }
  };
#pragma unroll
  for (int i = 0; i < 2; ++i)
#pragma unroll
    for (int j = 0; j < 8; ++j) acc[i][j] = (f32x4){0.f, 0.f, 0.f, 0.f};
  STAGE_A1(0, 0);
  STAGE_B1(0, 0);
  for (int t = 0; t < 16; ++t) {
    __syncthreads();
    if (t + 1 < 16) { STAGE_A1((t + 1) & 1, t + 1); STAGE_B1((t + 1) & 1, t + 1); }
    int cur = t & 1;
    short8 af[2];
#pragma unroll
    for (int f = 0; f < 2; ++f) {
      int nl = wp * 32 + f * 16 + (l & 15);
      af[f] =
          *(const short8*)&As[cur * 4096 + nl * 32 + 8 * ((l >> 4) ^ ((nl >> 1) & 3))];
    }
#pragma unroll
    for (int mf = 0; mf < 8; ++mf) {
      int ml = wm * 128 + mf * 16 + (l & 15);
      short8 bf =
          *(const short8*)&Bs[cur * 8192 + ml * 32 + 8 * ((l >> 4) ^ ((ml >> 1) & 3))];
      acc[0][mf] =
          __builtin_amdgcn_mfma_f32_16x16x32_bf16(af[0], bf, acc[0][mf], 0, 0, 0);
      acc[1][mf] =
          __builtin_amdgcn_mfma_f32_16x16x32_bf16(af[1], bf, acc[1][mf], 0, 0, 0);
    }
  }
#pragma unroll
  for (int mf = 0; mf < 8; ++mf) {
    int ch = wm * 128 + mf * 16 + (l & 15);
    float gm = g1[ch], bm = b1[ch];
    int tq = ch >> 5, slot = (ch >> 3) & 3, wi = ch & 7;
#pragma unroll
    for (int i = 0; i < 2; ++i) {
#pragma unroll
      for (int r = 0; r < 4; ++r) {
        int p = wp * 32 + i * 16 + (l >> 4) * 4 + r;
        Q1f[tq][p * 32 + 8 * (slot ^ ((p >> 1) & 3)) + wi] =
            f2bf(fmaxf(acc[i][mf][r] * gm + bm, 0.f));
      }
    }
  }

  // ---- stage 1b: q2, K=256, A from Q1f ----
  auto STAGE_B2 = [&](int buf, int t) {
    int k0 = t * 32;
#pragma unroll
    for (int q = 0; q < 2; ++q) {
      int e = q * 4096 + tid * 8;
      int rl = e >> 5, sl = (e >> 3) & 3;
      gload16(W2 + (size_t)rl * CTC + k0 + 8 * (sl ^ ((rl >> 1) & 3)),
              &Bs[buf * 8192 + q * 4096 + w * 512]);
    }
  };
#pragma unroll
  for (int i = 0; i < 2; ++i)
#pragma unroll
    for (int j = 0; j < 8; ++j) acc[i][j] = (f32x4){0.f, 0.f, 0.f, 0.f};
  STAGE_B2(0, 0);
  for (int t = 0; t < 8; ++t) {
    __syncthreads();  // Q1f visible (t=0); Bs[cur] staged; prev Bs reads done
    if (t + 1 < 8) STAGE_B2((t + 1) & 1, t + 1);
    int cur = t & 1;
    short8 af[2];
#pragma unroll
    for (int f = 0; f < 2; ++f) {
      int nl = wp * 32 + f * 16 + (l & 15);
      af[f] = *(const short8*)&Q1f[t][nl * 32 + 8 * ((l >> 4) ^ ((nl >> 1) & 3))];
    }
#pragma unroll
    for (int mf = 0; mf < 8; ++mf) {
      int ml = wm * 128 + mf * 16 + (l & 15);
      short8 bf =
          *(const short8*)&Bs[cur * 8192 + ml * 32 + 8 * ((l >> 4) ^ ((ml >> 1) & 3))];
      acc[0][mf] =
          __builtin_amdgcn_mfma_f32_16x16x32_bf16(af[0], bf, acc[0][mf], 0, 0, 0);
      acc[1][mf] =
          __builtin_amdgcn_mfma_f32_16x16x32_bf16(af[1], bf, acc[1][mf], 0, 0, 0);
    }
  }
  __syncthreads();  // all waves' Q1f reads done before overlay write
#pragma unroll
  for (int mf = 0; mf < 8; ++mf) {
    int ch = wm * 128 + mf * 16 + (l & 15);
    float gm = g2[ch], bm = b2[ch];
    int tq = ch >> 5, slot = (ch >> 3) & 3, wi = ch & 7;
#pragma unroll
    for (int i = 0; i < 2; ++i) {
#pragma unroll
      for (int r = 0; r < 4; ++r) {
        int p = wp * 32 + i * 16 + (l >> 4) * 4 + r;
        Q1f[tq][p * 32 + 8 * (slot ^ ((p >> 1) & 3)) + wi] =
            f2bf(fmaxf(acc[i][mf][r] * gm + bm, 0.f));
      }
    }
  }
  __syncthreads();  // Qf (=q2) complete

  // ---- stage 2: sim = q2 . Kcls (8 waves x 16 pixels) ----
  f32x4 a2[2];
  a2[0] = (f32x4){0.f, 0.f, 0.f, 0.f};
  a2[1] = (f32x4){0.f, 0.f, 0.f, 0.f};
  for (int t = 0; t < 8; ++t) {
    int nl = w * 16 + (l & 15);
    short8 aq =
        *(const short8*)&Q1f[t][nl * 32 + 8 * ((l >> 4) ^ ((nl >> 1) & 3))];
    int s = t * 4 + (l >> 4);
#pragma unroll
    for (int j = 0; j < 2; ++j) {
      int ml = j * 16 + (l & 15);
      short8 bk = *(const short8*)&Kl2[(s * 32 + ml) * 8];
      a2[j] = __builtin_amdgcn_mfma_f32_16x16x32_bf16(aq, bk, a2[j], 0, 0, 0);
    }
  }
  __syncthreads();  // RC (As/Bs) dead -> becomes simT/Pl
#pragma unroll
  for (int j = 0; j < 2; ++j) {
    int m = j * 16 + (l & 15);
    if (m < NK) {
#pragma unroll
      for (int r = 0; r < 4; ++r) {
        int p = w * 16 + (l >> 4) * 4 + r;
        simT[p * 33 + m] = a2[j][r];
      }
    }
  }
  __syncthreads();
  if (tid < 128) {
    float sims[NK];
#pragma unroll
    for (int k = 0; k < NK; ++k) sims[k] = simT[tid * 33 + k] * 0.0625f;
    float m = -1e30f;
#pragma unroll
    for (int k = 0; k < NK; ++k)
      if (cntl[k] > 0.f) m = fmaxf(m, sims[k]);
    float d = 0.f;
#pragma unroll
    for (int k = 0; k < NK; ++k) {
      float e = (cntl[k] > 0.f) ? expf(sims[k] - m) : 0.f;
      sims[k] = cntl[k] * e;
      d += sims[k];
    }
    float inv = 1.f / d;
#pragma unroll
    for (int s = 0; s < 4; ++s) {
      union { short8 v; unsigned short u8[8]; } pk;
#pragma unroll
      for (int j = 0; j < 8; ++j) {
        int k = s * 8 + j;
        pk.u8[j] = (k < NK) ? f2bf(sims[k] * inv) : (unsigned short)0;
      }
      *(short8*)&Pl[(s * 128 + tid) * 8] = pk.v;
    }
  }
  __syncthreads();
  // ---- stage 4: PV -> ctx bf16 -> Q1f (verified chunk-swizzle write) ----
  short8 ap;
  {
    int nl = w * 16 + (l & 15);
    ap = *(const short8*)&Pl[((l >> 4) * 128 + nl) * 8];
  }
#pragma unroll
  for (int mc = 0; mc < 4; ++mc) {
#pragma unroll
    for (int mf = 0; mf < 4; ++mf) {
      int ml = mc * 64 + mf * 16 + (l & 15);
      short8 bv = *(const short8*)&Vl2[((l >> 4) * 256 + ml) * 8];
      f32x4 z = {0.f, 0.f, 0.f, 0.f};
      f32x4 o = __builtin_amdgcn_mfma_f32_16x16x32_bf16(ap, bv, z, 0, 0, 0);
      int tq = ml >> 5, slot = (ml >> 3) & 3, wi = ml & 7;
#pragma unroll
      for (int r = 0; r < 4; ++r) {
        int p = w * 16 + (l >> 4) * 4 + r;
        Q1f[tq][p * 32 + 8 * (slot ^ ((p >> 1) & 3)) + wi] = f2bf(o[r]);
      }
    }
  }

  // ---- stage 5: out = relu(og*(Wo.ctx)+ob), K=256, M=512 in 2 halves,
  //      WoBuf dbuf [2][16KB], one barrier/step (verified round 18) ----
  auto STAGE_WO = [&](int hm, int buf, int t) {  // 16 KB: 2 gloads/thread
    int k0 = t * 32;
#pragma unroll
    for (int q = 0; q < 2; ++q) {
      int e = q * 4096 + tid * 8;
      int rl = e >> 5, sl = (e >> 3) & 3;
      gload16(Wo + (size_t)(hm * 256 + rl) * CTC + k0 + 8 * (sl ^ ((rl >> 1) & 3)),
              &WoBuf[buf * 8192 + q * 4096 + w * 512]);
    }
  };
  float* outb = out + (size_t)b * CIN * HW;
  STAGE_WO(0, 0, 0);
  for (int hm = 0; hm < 2; ++hm) {
#pragma unroll
    for (int i = 0; i < 2; ++i)
#pragma unroll
      for (int j = 0; j < 8; ++j) acc[i][j] = (f32x4){0.f, 0.f, 0.f, 0.f};
    for (int t = 0; t < 8; ++t) {
      __syncthreads();  // t=0,hm=0: all PV Q1f writes + Pl reads complete;
                        // else: prev WoBuf[cur] reads complete + loads drained
      if (t + 1 < 8) STAGE_WO(hm, (t + 1) & 1, t + 1);
      int cur = t & 1;
      short8 af[2];
#pragma unroll
      for (int f = 0; f < 2; ++f) {
        int nl = wp * 32 + f * 16 + (l & 15);
        af[f] =
            *(const short8*)&Q1f[t][nl * 32 + 8 * ((l >> 4) ^ ((nl >> 1) & 3))];
      }
#pragma unroll
      for (int mf = 0; mf < 8; ++mf) {
        int ml = wm * 128 + mf * 16 + (l & 15);  // row within the 256-half
        short8 bf =
            *(const short8*)&WoBuf[cur * 8192 + ml * 32 + 8 * ((l >> 4) ^ ((ml >> 1) & 3))];
        acc[0][mf] =
            __builtin_amdgcn_mfma_f32_16x16x32_bf16(af[0], bf, acc[0][mf], 0, 0, 0);
        acc[1][mf] =
            __builtin_amdgcn_mfma_f32_16x16x32_bf16(af[1], bf, acc[1][mf], 0, 0, 0);
      }
    }
    if (hm == 0) STAGE_WO(1, 0, 0);
#pragma unroll
    for (int mf = 0; mf < 8; ++mf) {
      int co = hm * 256 + wm * 128 + mf * 16 + (l & 15);
      float gm = og[co], bm = ob[co];
#pragma unroll
      for (int i = 0; i < 2; ++i) {
        int n = p0 + wp * 32 + i * 16 + (l >> 4) * 4;
        float4 o;
        o.x = fmaxf(acc[i][mf][0] * gm + bm, 0.f);
        o.y = fmaxf(acc[i][mf][1] * gm + bm, 0.f);
        o.z = fmaxf(acc[i][mf][2] * gm + bm, 0.f);
        o.w = fmaxf(acc[i][mf][3] * gm + bm, 0.f);
        *(float4*)&outb[(size_t)co * HW + n] = o;
      }
    }
  }
}

// ---------------------------------------------------------------------------
extern "C" void kernel_launch(void* const* d_in, const int* in_sizes, int n_in,
                              void* d_out, int out_size, void* d_ws, size_t ws_size,
                              hipStream_t stream) {
  const float* x = (const float*)d_in[0];
  const float* preds = (const float*)d_in[1];
  const float* q_w1 = (const float*)d_in[3];
  const float* q_g1 = (const float*)d_in[4];
  const float* q_b1 = (const float*)d_in[5];
  const float* q_w2 = (const float*)d_in[6];
  const float* q_g2 = (const float*)d_in[7];
  const float* q_b2 = (const float*)d_in[8];
  const float* k_w1 = (const float*)d_in[9];
  const float* k_g1 = (const float*)d_in[10];
  const float* k_b1 = (const float*)d_in[11];
  const float* k_w2 = (const float*)d_in[12];
  const float* k_g2 = (const float*)d_in[13];
  const float* k_b2 = (const float*)d_in[14];
  const float* v_w = (const float*)d_in[15];
  const float* v_g = (const float*)d_in[16];
  const float* v_b = (const float*)d_in[17];
  const float* o_w = (const float*)d_in[18];
  const float* o_g = (const float*)d_in[19];
  const float* o_b = (const float*)d_in[20];
  float* out = (float*)d_out;

  char* base = (char*)d_ws;
  unsigned short* xT = (unsigned short*)base;               // 33,554,432 B
  char* f32r = base + 33554432;
  float* cls_feat = (float*)f32r;                            // 311,296 B
  unsigned short* KclsP = (unsigned short*)(f32r + 311296);  // 131,072 B
  unsigned short* VclsP = (unsigned short*)(f32r + 442368);  // 131,072 B
  unsigned short* wb1 = (unsigned short*)(f32r + 573440);    // 262,144 B
  unsigned short* wb2 = (unsigned short*)(f32r + 835584);    // 131,072 B
  unsigned short* wbo = (unsigned short*)(f32r + 966656);    // 262,144 B
  float* h1g = (float*)(f32r + 1228800);                     // 155,648 B
  float* bestg = (float*)(f32r + 1384448);                   // 131,072 B
  int* clsg = (int*)(f32r + 1515520);                        // 131,072 B
  unsigned int* Mu_part = (unsigned int*)(f32r + 1646592);   // 16,384 B
  unsigned int* cnt_part = (unsigned int*)(f32r + 1662976);  // 16,384 B
  float* Zf_part = (float*)(f32r + 1679360);                 // 16,384 B

  wk1a<<<448, 256, 0, stream>>>(q_w1, q_w2, o_w, wb1, wb2, wbo,
                                (uint4*)cls_feat, preds, bestg, clsg, Mu_part,
                                cnt_part);
  k1b<<<dim3(16, NB), 256, 0, stream>>>(bestg, clsg, Mu_part, Zf_part);
  xk2<<<dim3(8, 8, NB), 256, 0, stream>>>(x, bestg, clsg, Zf_part, xT,
                                          cls_feat);
  k3a<<<dim3(4, NB * NK), 256, 0, stream>>>(cls_feat, k_w1, k_g1, k_b1, v_w,
                                            v_g, v_b, h1g, VclsP);
  k3b<<<dim3(4, NB * NK), 256, 0, stream>>>(h1g, k_w2, k_g2, k_b2, KclsP);
  g1g2k5o<<<dim3(HW / 128, NB), 512, 0, stream>>>(xT, wb1, q_g1, q_b1, wb2,
                                                  q_g2, q_b2, KclsP, VclsP,
                                                  cnt_part, wbo, o_g, o_b,
                                                  out);
}

// Round 20
// 110.628 us; speedup vs baseline: 1.0472x; 1.0033x over previous
//
#include <hip/hip_runtime.h>
#include <math.h>

#define HW 4096
#define NB 8
#define NK 19
#define CIN 512
#define CTC 256

typedef __attribute__((ext_vector_type(8))) short short8;
typedef __attribute__((ext_vector_type(4))) float f32x4;

__device__ inline unsigned short f2bf(float x) {
  unsigned u = __float_as_uint(x);
  return (unsigned short)((u + 0x7fffu + ((u >> 16) & 1u)) >> 16);  // RNE
}
__device__ inline float bf2f(unsigned short h) {
  return __uint_as_float(((unsigned)h) << 16);
}
__device__ inline void gload16(const void* g, void* l) {
  __builtin_amdgcn_global_load_lds(
      (const __attribute__((address_space(1))) void*)g,
      (__attribute__((address_space(3))) void*)l, 16, 0, 0);
}

// ---------------------------------------------------------------------------
// wk1a (verified round 12): weight convert + cls_feat zero + k1a partials.
// ---------------------------------------------------------------------------
__global__ __launch_bounds__(256) void wk1a(
    const float* __restrict__ w1, const float* __restrict__ w2,
    const float* __restrict__ wo, unsigned short* __restrict__ wb1,
    unsigned short* __restrict__ wb2, unsigned short* __restrict__ wbo,
    uint4* __restrict__ cls_feat_z, const float* __restrict__ preds,
    float* __restrict__ bestg, int* __restrict__ clsg,
    unsigned int* __restrict__ Mu_part, unsigned int* __restrict__ cnt_part) {
  __shared__ unsigned int Mw[NK];
  __shared__ unsigned int Cw[NK];
  int bx = blockIdx.x;
  int tid = threadIdx.x;
  if (bx < 320) {
    int gid = bx * 256 + tid;
    int i = gid * 4;  // [0, 327680)
    const float* src;
    unsigned short* dst;
    int off;
    if (i < 131072) { src = w1; dst = wb1; off = i; }
    else if (i < 196608) { src = w2; dst = wb2; off = i - 131072; }
    else { src = wo; dst = wbo; off = i - 196608; }
    float4 v = *(const float4*)(src + off);
    dst[off + 0] = f2bf(v.x);
    dst[off + 1] = f2bf(v.y);
    dst[off + 2] = f2bf(v.z);
    dst[off + 3] = f2bf(v.w);
    uint4 z = {0u, 0u, 0u, 0u};
    for (int j = gid; j < 19456; j += 81920) cls_feat_z[j] = z;
  } else {
    int bq = bx - 320;
    int b = bq >> 4, pblk = bq & 15;
    if (tid < NK) { Mw[tid] = 0u; Cw[tid] = 0u; }
    __syncthreads();
    int p = pblk * 256 + tid;
    const float* pb = preds + (size_t)b * NK * HW;
    float best = pb[p];
    int bi = 0;
#pragma unroll
    for (int k = 1; k < NK; ++k) {
      float v = pb[k * HW + p];
      if (v > best) { best = v; bi = k; }  // strict > = jnp.argmax first-index
    }
    bestg[b * HW + p] = best;
    clsg[b * HW + p] = bi;
    unsigned fb = __float_as_uint(best);
    unsigned key = (fb & 0x80000000u) ? ~fb : (fb | 0x80000000u);
    atomicMax(&Mw[bi], key);
    atomicAdd(&Cw[bi], 1u);
    __syncthreads();
    if (tid < 32) {
      Mu_part[(b * 16 + pblk) * 32 + tid] = (tid < NK) ? Mw[tid] : 0u;
      cnt_part[(b * 16 + pblk) * 32 + tid] = (tid < NK) ? Cw[tid] : 0u;
    }
  }
}

// ---------------------------------------------------------------------------
// k1b (verified round 12).
// ---------------------------------------------------------------------------
__global__ __launch_bounds__(256) void k1b(
    float* __restrict__ bestg, const int* __restrict__ clsg,
    const unsigned int* __restrict__ Mu_part, float* __restrict__ Zf_part) {
  int b = blockIdx.y, pblk = blockIdx.x;
  int tid = threadIdx.x;
  __shared__ float Mf[NK];
  __shared__ float Zw[NK];
  if (tid < NK) {
    unsigned key = 0u;
#pragma unroll
    for (int j = 0; j < 16; ++j) {
      unsigned v = Mu_part[(b * 16 + j) * 32 + tid];
      key = (v > key) ? v : key;
    }
    float m = -1e30f;
    if (key) {
      unsigned fb = (key & 0x80000000u) ? (key & 0x7fffffffu) : ~key;
      m = __uint_as_float(fb);
    }
    Mf[tid] = m;
    Zw[tid] = 0.f;
  }
  __syncthreads();
  int p = pblk * 256 + tid;
  int c = clsg[b * HW + p];
  float e = expf(bestg[b * HW + p] - Mf[c]);
  bestg[b * HW + p] = e;
  atomicAdd(&Zw[c], e);
  __syncthreads();
  if (tid < 32) Zf_part[(b * 16 + pblk) * 32 + tid] = (tid < NK) ? Zw[tid] : 0.f;
}

// ---------------------------------------------------------------------------
// FUSED xk2 (verified round 19, T14 staging).
// ---------------------------------------------------------------------------
__global__ __launch_bounds__(256) void xk2(
    const float* __restrict__ x, const float* __restrict__ eg,
    const int* __restrict__ clsg, const float* __restrict__ Zf_part,
    unsigned short* __restrict__ xT, float* __restrict__ cls_feat) {
  __shared__ float tile[64][65];
  __shared__ unsigned short Bs[32 * 516];
  __shared__ float Zl[NK];
  int b = blockIdx.z, c0 = blockIdx.y * 64, pbase = blockIdx.x * 512;
  int tid = threadIdx.x;
  int l = tid & 63, w = tid >> 6;
  if (tid < NK) {
    float s = 0.f;
#pragma unroll
    for (int j = 0; j < 16; ++j) s += Zf_part[(b * 16 + j) * 32 + tid];
    Zl[tid] = s;
  }
  {
    uint4 z = {0u, 0u, 0u, 0u};
    for (int i = tid; i < 2064; i += 256) ((uint4*)Bs)[i] = z;
  }
  __syncthreads();
  for (int i = tid; i < 512; i += 256) {
    int c = clsg[b * HW + pbase + i];
    Bs[c * 516 + i] = f2bf(eg[b * HW + pbase + i] / Zl[c]);
  }
  f32x4 acc[2];
  acc[0] = (f32x4){0.f, 0.f, 0.f, 0.f};
  acc[1] = (f32x4){0.f, 0.f, 0.f, 0.f};
  int cbase = w * 16;
  int clr = (tid >> 4);
  int plr = (tid & 15) * 4;
  float4 rv[4];
#pragma unroll
  for (int r = 0; r < 4; ++r)
    rv[r] = *(const float4*)&x[((size_t)b * CIN + c0 + r * 16 + clr) * HW +
                               pbase + plr];
  for (int s = 0; s < 8; ++s) {
    __syncthreads();
#pragma unroll
    for (int r = 0; r < 4; ++r) {
      int cl = r * 16 + clr;
      tile[cl][plr + 0] = rv[r].x;
      tile[cl][plr + 1] = rv[r].y;
      tile[cl][plr + 2] = rv[r].z;
      tile[cl][plr + 3] = rv[r].w;
    }
    float4 rv2[4];
    if (s + 1 < 8) {
      int psn = pbase + (s + 1) * 64;
#pragma unroll
      for (int r = 0; r < 4; ++r)
        rv2[r] = *(const float4*)&x[((size_t)b * CIN + c0 + r * 16 + clr) * HW +
                                    psn + plr];
    }
    __syncthreads();
    int ps = pbase + s * 64;
#pragma unroll
    for (int j = 0; j < 16; ++j) {
      int ploc = j * 4 + w;
      xT[((size_t)b * HW + ps + ploc) * CIN + c0 + l] = f2bf(tile[l][ploc]);
    }
#pragma unroll
    for (int ch = 0; ch < 2; ++ch) {
      int pt = ch * 32 + (l >> 4) * 8;
      union { short8 v; unsigned short u[8]; } af;
      const float* tp = &tile[cbase + (l & 15)][pt];
#pragma unroll
      for (int j = 0; j < 8; ++j) af.u[j] = f2bf(tp[j]);
      int pg = s * 64 + pt;
#pragma unroll
      for (int mf = 0; mf < 2; ++mf) {
        short8 bf = *(const short8*)&Bs[(mf * 16 + (l & 15)) * 516 + pg];
        acc[mf] =
            __builtin_amdgcn_mfma_f32_16x16x32_bf16(af.v, bf, acc[mf], 0, 0, 0);
      }
    }
#pragma unroll
    for (int r = 0; r < 4; ++r) rv[r] = rv2[r];
  }
#pragma unroll
  for (int mf = 0; mf < 2; ++mf) {
    int k = mf * 16 + (l & 15);
    if (k < NK) {
#pragma unroll
      for (int r = 0; r < 4; ++r) {
        int c = c0 + cbase + (l >> 4) * 4 + r;
        atomicAdd(&cls_feat[((size_t)b * NK + k) * CIN + c], acc[mf][r]);
      }
    }
  }
}

// ---------------------------------------------------------------------------
// K3a (verified round 17): h1 + VclsP pre-packed bf16 (Vl2 slot-major).
// ---------------------------------------------------------------------------
__global__ __launch_bounds__(256) void k3a(
    const float* __restrict__ cls_feat, const float* __restrict__ kw1,
    const float* __restrict__ kg1, const float* __restrict__ kb1,
    const float* __restrict__ vw, const float* __restrict__ vg,
    const float* __restrict__ vb, float* __restrict__ h1g,
    unsigned short* __restrict__ VclsP) {
  int bk = blockIdx.y;
  int b = bk / NK, kc = bk % NK;
  int q = blockIdx.x;
  __shared__ float cf[CIN];
  int tid = threadIdx.x;
  const float* row = cls_feat + (size_t)bk * CIN;
  for (int i = tid; i < CIN; i += 256) cf[i] = row[i];
  __syncthreads();
  int o = tid >> 1, half = tid & 1;
  int col = q * 64 + (o & 63);
  const float* w =
      (o < 64) ? &kw1[(size_t)col * CIN] : &vw[(size_t)col * CIN];
  int base = half * 256;
  float acc[4] = {0.f, 0.f, 0.f, 0.f};
#pragma unroll 8
  for (int i = 0; i < 64; ++i) {
    float4 w4 = *(const float4*)&w[base + i * 4];
    const float* c4 = &cf[base + i * 4];
    acc[i & 3] += w4.x * c4[0] + w4.y * c4[1] + w4.z * c4[2] + w4.w * c4[3];
  }
  float s = (acc[0] + acc[1]) + (acc[2] + acc[3]);
  s += __shfl_xor(s, 1);
  if (half == 0) {
    if (o < 64) {
      h1g[(size_t)bk * CTC + col] = fmaxf(s * kg1[col] + kb1[col], 0.f);
    } else {
      VclsP[(size_t)b * 8192 + ((kc >> 3) * 256 + col) * 8 + (kc & 7)] =
          f2bf(fmaxf(s * vg[col] + vb[col], 0.f));
    }
  }
}

// ---------------------------------------------------------------------------
// K3b (verified round 17): KclsP pre-packed bf16 (Kl2 slot-major).
// ---------------------------------------------------------------------------
__global__ __launch_bounds__(256) void k3b(
    const float* __restrict__ h1g, const float* __restrict__ kw2,
    const float* __restrict__ kg2, const float* __restrict__ kb2,
    unsigned short* __restrict__ KclsP) {
  int bk = blockIdx.y;
  int b = bk / NK, kc = bk % NK;
  int q = blockIdx.x;
  __shared__ float h1[CTC];
  int tid = threadIdx.x;
  const float* row = h1g + (size_t)bk * CTC;
  if (tid < CTC) h1[tid] = row[tid];
  __syncthreads();
  int o = tid >> 2, part = tid & 3;
  int col = q * 64 + o;
  const float* w = &kw2[(size_t)col * CTC + part * 64];
  const float* c = &h1[part * 64];
  float acc[4] = {0.f, 0.f, 0.f, 0.f};
#pragma unroll
  for (int i = 0; i < 16; ++i) {
    float4 w4 = *(const float4*)&w[i * 4];
    acc[i & 3] += w4.x * c[i * 4] + w4.y * c[i * 4 + 1] + w4.z * c[i * 4 + 2] +
                  w4.w * c[i * 4 + 3];
  }
  float s = (acc[0] + acc[1]) + (acc[2] + acc[3]);
  s += __shfl_xor(s, 1);
  s += __shfl_xor(s, 2);
  if (part == 0)
    KclsP[(size_t)b * 8192 + ((col >> 3) * 32 + kc) * 8 + (col & 7)] =
        f2bf(fmaxf(s * kg2[col] + kb2[col], 0.f));
}

// ---------------------------------------------------------------------------
// FUSED g1g2k5o — round-18 verified structure; stages 1a/1b converted to the
// T4 counted-vmcnt pattern: prefetched global_load_lds stay in flight across
// raw s_barriers (no vmcnt(0) drain); per-step {issue -> vmcnt(N) lgkm(0) ->
// sched_barrier -> s_barrier -> compute -> s_barrier}. Stages 2-5 unchanged.
// ---------------------------------------------------------------------------
__global__ __launch_bounds__(512, 1) void g1g2k5o(
    const unsigned short* __restrict__ xT, const unsigned short* __restrict__ W1,
    const float* __restrict__ g1, const float* __restrict__ b1,
    const unsigned short* __restrict__ W2, const float* __restrict__ g2,
    const float* __restrict__ b2, const unsigned short* __restrict__ KclsP,
    const unsigned short* __restrict__ VclsP,
    const unsigned int* __restrict__ cnt_part,
    const unsigned short* __restrict__ Wo, const float* __restrict__ og,
    const float* __restrict__ ob, float* __restrict__ out) {
  __shared__ __align__(16) char RC[49152];  // As+Bs dbuf | simT+Pl | WoBuf dbuf
  __shared__ __align__(16) unsigned short Q1f[8][4096];      // q1 -> q2 -> ctx
  __shared__ __align__(16) unsigned short Kl2[32 * 32 * 8];  // 16 KB
  __shared__ __align__(16) unsigned short Vl2[4 * 256 * 8];  // 16 KB
  __shared__ float cntl[NK];
  unsigned short* As = (unsigned short*)RC;            // [2][128*32]
  unsigned short* Bs = (unsigned short*)(RC + 16384);  // [2][256*32]
  float* simT = (float*)RC;                            // phase-2 overlay
  unsigned short* Pl = (unsigned short*)(RC + 16896);
  unsigned short* WoBuf = (unsigned short*)RC;         // stage-5: [2][256*32]

  int b = blockIdx.y;
  int p0 = blockIdx.x * 128;
  int tid = threadIdx.x;
  int l = tid & 63, w = tid >> 6;  // 8 waves
  int wp = w & 3, wm = w >> 2;     // GEMM decomposition
  const unsigned short* xTb = xT + ((size_t)b * HW + p0) * CIN;

  // K/V staging: vectorized copy of pre-packed layouts (verified round 17)
  for (int i = tid; i < 1024; i += 512) {
    *(short8*)&Kl2[i * 8] = *(const short8*)&KclsP[(size_t)b * 8192 + i * 8];
    *(short8*)&Vl2[i * 8] = *(const short8*)&VclsP[(size_t)b * 8192 + i * 8];
  }
  if (tid < NK) {
    unsigned int s = 0u;
#pragma unroll
    for (int j = 0; j < 16; ++j) s += cnt_part[(b * 16 + j) * 32 + tid];
    cntl[tid] = (float)s;
  }

  f32x4 acc[2][8];

  // ---- stage 1a: q1, K=512 (counted-vmcnt pipeline; 3 loads/thread/step) ----
  auto STAGE_A1 = [&](int buf, int t) {
    int k0 = t * 32;
    int e = tid * 8;
    int rl = e >> 5, sl = (e >> 3) & 3;
    gload16(xTb + (size_t)rl * CIN + k0 + 8 * (sl ^ ((rl >> 1) & 3)),
            &As[buf * 4096 + w * 512]);
  };
  auto STAGE_B1 = [&](int buf, int t) {
    int k0 = t * 32;
#pragma unroll
    for (int q = 0; q < 2; ++q) {
      int e = q * 4096 + tid * 8;
      int rl = e >> 5, sl = (e >> 3) & 3;
      gload16(W1 + (size_t)rl * CIN + k0 + 8 * (sl ^ ((rl >> 1) & 3)),
              &Bs[buf * 8192 + q * 4096 + w * 512]);
    }
  };
#pragma unroll
  for (int i = 0; i < 2; ++i)
#pragma unroll
    for (int j = 0; j < 8; ++j) acc[i][j] = (f32x4){0.f, 0.f, 0.f, 0.f};
  STAGE_A1(0, 0);
  STAGE_B1(0, 0);
  for (int t = 0; t < 16; ++t) {
    if (t + 1 < 16) {
      STAGE_A1((t + 1) & 1, t + 1);
      STAGE_B1((t + 1) & 1, t + 1);
      asm volatile("s_waitcnt vmcnt(3) lgkmcnt(0)" ::: "memory");
    } else {
      asm volatile("s_waitcnt vmcnt(0) lgkmcnt(0)" ::: "memory");
    }
    __builtin_amdgcn_sched_barrier(0);
    __builtin_amdgcn_s_barrier();  // buf[t&1] complete for all waves
    int cur = t & 1;
    short8 af[2];
#pragma unroll
    for (int f = 0; f < 2; ++f) {
      int nl = wp * 32 + f * 16 + (l & 15);
      af[f] =
          *(const short8*)&As[cur * 4096 + nl * 32 + 8 * ((l >> 4) ^ ((nl >> 1) & 3))];
    }
#pragma unroll
    for (int mf = 0; mf < 8; ++mf) {
      int ml = wm * 128 + mf * 16 + (l & 15);
      short8 bf =
          *(const short8*)&Bs[cur * 8192 + ml * 32 + 8 * ((l >> 4) ^ ((ml >> 1) & 3))];
      acc[0][mf] =
          __builtin_amdgcn_mfma_f32_16x16x32_bf16(af[0], bf, acc[0][mf], 0, 0, 0);
      acc[1][mf] =
          __builtin_amdgcn_mfma_f32_16x16x32_bf16(af[1], bf, acc[1][mf], 0, 0, 0);
    }
    __builtin_amdgcn_s_barrier();  // reads of buf[t&1] done before overwrite
  }
#pragma unroll
  for (int mf = 0; mf < 8; ++mf) {
    int ch = wm * 128 + mf * 16 + (l & 15);
    float gm = g1[ch], bm = b1[ch];
    int tq = ch >> 5, slot = (ch >> 3) & 3, wi = ch & 7;
#pragma unroll
    for (int i = 0; i < 2; ++i) {
#pragma unroll
      for (int r = 0; r < 4; ++r) {
        int p = wp * 32 + i * 16 + (l >> 4) * 4 + r;
        Q1f[tq][p * 32 + 8 * (slot ^ ((p >> 1) & 3)) + wi] =
            f2bf(fmaxf(acc[i][mf][r] * gm + bm, 0.f));
      }
    }
  }

  // ---- stage 1b: q2, K=256, A from Q1f (counted-vmcnt; 2 loads/step) ----
  auto STAGE_B2 = [&](int buf, int t) {
    int k0 = t * 32;
#pragma unroll
    for (int q = 0; q < 2; ++q) {
      int e = q * 4096 + tid * 8;
      int rl = e >> 5, sl = (e >> 3) & 3;
      gload16(W2 + (size_t)rl * CTC + k0 + 8 * (sl ^ ((rl >> 1) & 3)),
              &Bs[buf * 8192 + q * 4096 + w * 512]);
    }
  };
#pragma unroll
  for (int i = 0; i < 2; ++i)
#pragma unroll
    for (int j = 0; j < 8; ++j) acc[i][j] = (f32x4){0.f, 0.f, 0.f, 0.f};
  STAGE_B2(0, 0);
  for (int t = 0; t < 8; ++t) {
    if (t + 1 < 8) {
      STAGE_B2((t + 1) & 1, t + 1);
      asm volatile("s_waitcnt vmcnt(2) lgkmcnt(0)" ::: "memory");
    } else {
      asm volatile("s_waitcnt vmcnt(0) lgkmcnt(0)" ::: "memory");
    }
    __builtin_amdgcn_sched_barrier(0);
    __builtin_amdgcn_s_barrier();  // Bs[t&1] loaded; Q1f(q1) published (t=0)
    int cur = t & 1;
    short8 af[2];
#pragma unroll
    for (int f = 0; f < 2; ++f) {
      int nl = wp * 32 + f * 16 + (l & 15);
      af[f] = *(const short8*)&Q1f[t][nl * 32 + 8 * ((l >> 4) ^ ((nl >> 1) & 3))];
    }
#pragma unroll
    for (int mf = 0; mf < 8; ++mf) {
      int ml = wm * 128 + mf * 16 + (l & 15);
      short8 bf =
          *(const short8*)&Bs[cur * 8192 + ml * 32 + 8 * ((l >> 4) ^ ((ml >> 1) & 3))];
      acc[0][mf] =
          __builtin_amdgcn_mfma_f32_16x16x32_bf16(af[0], bf, acc[0][mf], 0, 0, 0);
      acc[1][mf] =
          __builtin_amdgcn_mfma_f32_16x16x32_bf16(af[1], bf, acc[1][mf], 0, 0, 0);
    }
    __builtin_amdgcn_s_barrier();  // Bs/Q1f reads done before next write
  }
  // epilogue: q2 -> Q1f overlay (prev loop's trailing barrier protects RAW/WAR)
#pragma unroll
  for (int mf = 0; mf < 8; ++mf) {
    int ch = wm * 128 + mf * 16 + (l & 15);
    float gm = g2[ch], bm = b2[ch];
    int tq = ch >> 5, slot = (ch >> 3) & 3, wi = ch & 7;
#pragma unroll
    for (int i = 0; i < 2; ++i) {
#pragma unroll
      for (int r = 0; r < 4; ++r) {
        int p = wp * 32 + i * 16 + (l >> 4) * 4 + r;
        Q1f[tq][p * 32 + 8 * (slot ^ ((p >> 1) & 3)) + wi] =
            f2bf(fmaxf(acc[i][mf][r] * gm + bm, 0.f));
      }
    }
  }
  __syncthreads();  // Qf (=q2) complete

  // ---- stage 2: sim = q2 . Kcls (8 waves x 16 pixels) ----
  f32x4 a2[2];
  a2[0] = (f32x4){0.f, 0.f, 0.f, 0.f};
  a2[1] = (f32x4){0.f, 0.f, 0.f, 0.f};
  for (int t = 0; t < 8; ++t) {
    int nl = w * 16 + (l & 15);
    short8 aq =
        *(const short8*)&Q1f[t][nl * 32 + 8 * ((l >> 4) ^ ((nl >> 1) & 3))];
    int s = t * 4 + (l >> 4);
#pragma unroll
    for (int j = 0; j < 2; ++j) {
      int ml = j * 16 + (l & 15);
      short8 bk = *(const short8*)&Kl2[(s * 32 + ml) * 8];
      a2[j] = __builtin_amdgcn_mfma_f32_16x16x32_bf16(aq, bk, a2[j], 0, 0, 0);
    }
  }
  __syncthreads();  // RC (As/Bs) dead -> becomes simT/Pl
#pragma unroll
  for (int j = 0; j < 2; ++j) {
    int m = j * 16 + (l & 15);
    if (m < NK) {
#pragma unroll
      for (int r = 0; r < 4; ++r) {
        int p = w * 16 + (l >> 4) * 4 + r;
        simT[p * 33 + m] = a2[j][r];
      }
    }
  }
  __syncthreads();
  if (tid < 128) {
    float sims[NK];
#pragma unroll
    for (int k = 0; k < NK; ++k) sims[k] = simT[tid * 33 + k] * 0.0625f;
    float m = -1e30f;
#pragma unroll
    for (int k = 0; k < NK; ++k)
      if (cntl[k] > 0.f) m = fmaxf(m, sims[k]);
    float d = 0.f;
#pragma unroll
    for (int k = 0; k < NK; ++k) {
      float e = (cntl[k] > 0.f) ? expf(sims[k] - m) : 0.f;
      sims[k] = cntl[k] * e;
      d += sims[k];
    }
    float inv = 1.f / d;
#pragma unroll
    for (int s = 0; s < 4; ++s) {
      union { short8 v; unsigned short u8[8]; } pk;
#pragma unroll
      for (int j = 0; j < 8; ++j) {
        int k = s * 8 + j;
        pk.u8[j] = (k < NK) ? f2bf(sims[k] * inv) : (unsigned short)0;
      }
      *(short8*)&Pl[(s * 128 + tid) * 8] = pk.v;
    }
  }
  __syncthreads();
  // ---- stage 4: PV -> ctx bf16 -> Q1f (verified chunk-swizzle write) ----
  short8 ap;
  {
    int nl = w * 16 + (l & 15);
    ap = *(const short8*)&Pl[((l >> 4) * 128 + nl) * 8];
  }
#pragma unroll
  for (int mc = 0; mc < 4; ++mc) {
#pragma unroll
    for (int mf = 0; mf < 4; ++mf) {
      int ml = mc * 64 + mf * 16 + (l & 15);
      short8 bv = *(const short8*)&Vl2[((l >> 4) * 256 + ml) * 8];
      f32x4 z = {0.f, 0.f, 0.f, 0.f};
      f32x4 o = __builtin_amdgcn_mfma_f32_16x16x32_bf16(ap, bv, z, 0, 0, 0);
      int tq = ml >> 5, slot = (ml >> 3) & 3, wi = ml & 7;
#pragma unroll
      for (int r = 0; r < 4; ++r) {
        int p = w * 16 + (l >> 4) * 4 + r;
        Q1f[tq][p * 32 + 8 * (slot ^ ((p >> 1) & 3)) + wi] = f2bf(o[r]);
      }
    }
  }

  // ---- stage 5: out = relu(og*(Wo.ctx)+ob), K=256, M=512 in 2 halves,
  //      WoBuf dbuf [2][16KB], one barrier/step (verified round 18) ----
  auto STAGE_WO = [&](int hm, int buf, int t) {  // 16 KB: 2 gloads/thread
    int k0 = t * 32;
#pragma unroll
    for (int q = 0; q < 2; ++q) {
      int e = q * 4096 + tid * 8;
      int rl = e >> 5, sl = (e >> 3) & 3;
      gload16(Wo + (size_t)(hm * 256 + rl) * CTC + k0 + 8 * (sl ^ ((rl >> 1) & 3)),
              &WoBuf[buf * 8192 + q * 4096 + w * 512]);
    }
  };
  float* outb = out + (size_t)b * CIN * HW;
  STAGE_WO(0, 0, 0);
  for (int hm = 0; hm < 2; ++hm) {
#pragma unroll
    for (int i = 0; i < 2; ++i)
#pragma unroll
      for (int j = 0; j < 8; ++j) acc[i][j] = (f32x4){0.f, 0.f, 0.f, 0.f};
    for (int t = 0; t < 8; ++t) {
      __syncthreads();  // t=0,hm=0: all PV Q1f writes + Pl reads complete;
                        // else: prev WoBuf[cur] reads complete + loads drained
      if (t + 1 < 8) STAGE_WO(hm, (t + 1) & 1, t + 1);
      int cur = t & 1;
      short8 af[2];
#pragma unroll
      for (int f = 0; f < 2; ++f) {
        int nl = wp * 32 + f * 16 + (l & 15);
        af[f] =
            *(const short8*)&Q1f[t][nl * 32 + 8 * ((l >> 4) ^ ((nl >> 1) & 3))];
      }
#pragma unroll
      for (int mf = 0; mf < 8; ++mf) {
        int ml = wm * 128 + mf * 16 + (l & 15);  // row within the 256-half
        short8 bf =
            *(const short8*)&WoBuf[cur * 8192 + ml * 32 + 8 * ((l >> 4) ^ ((ml >> 1) & 3))];
        acc[0][mf] =
            __builtin_amdgcn_mfma_f32_16x16x32_bf16(af[0], bf, acc[0][mf], 0, 0, 0);
        acc[1][mf] =
            __builtin_amdgcn_mfma_f32_16x16x32_bf16(af[1], bf, acc[1][mf], 0, 0, 0);
      }
    }
    if (hm == 0) STAGE_WO(1, 0, 0);
#pragma unroll
    for (int mf = 0; mf < 8; ++mf) {
      int co = hm * 256 + wm * 128 + mf * 16 + (l & 15);
      float gm = og[co], bm = ob[co];
#pragma unroll
      for (int i = 0; i < 2; ++i) {
        int n = p0 + wp * 32 + i * 16 + (l >> 4) * 4;
        float4 o;
        o.x = fmaxf(acc[i][mf][0] * gm + bm, 0.f);
        o.y = fmaxf(acc[i][mf][1] * gm + bm, 0.f);
        o.z = fmaxf(acc[i][mf][2] * gm + bm, 0.f);
        o.w = fmaxf(acc[i][mf][3] * gm + bm, 0.f);
        *(float4*)&outb[(size_t)co * HW + n] = o;
      }
    }
  }
}

// ---------------------------------------------------------------------------
extern "C" void kernel_launch(void* const* d_in, const int* in_sizes, int n_in,
                              void* d_out, int out_size, void* d_ws, size_t ws_size,
                              hipStream_t stream) {
  const float* x = (const float*)d_in[0];
  const float* preds = (const float*)d_in[1];
  const float* q_w1 = (const float*)d_in[3];
  const float* q_g1 = (const float*)d_in[4];
  const float* q_b1 = (const float*)d_in[5];
  const float* q_w2 = (const float*)d_in[6];
  const float* q_g2 = (const float*)d_in[7];
  const float* q_b2 = (const float*)d_in[8];
  const float* k_w1 = (const float*)d_in[9];
  const float* k_g1 = (const float*)d_in[10];
  const float* k_b1 = (const float*)d_in[11];
  const float* k_w2 = (const float*)d_in[12];
  const float* k_g2 = (const float*)d_in[13];
  const float* k_b2 = (const float*)d_in[14];
  const float* v_w = (const float*)d_in[15];
  const float* v_g = (const float*)d_in[16];
  const float* v_b = (const float*)d_in[17];
  const float* o_w = (const float*)d_in[18];
  const float* o_g = (const float*)d_in[19];
  const float* o_b = (const float*)d_in[20];
  float* out = (float*)d_out;

  char* base = (char*)d_ws;
  unsigned short* xT = (unsigned short*)base;               // 33,554,432 B
  char* f32r = base + 33554432;
  float* cls_feat = (float*)f32r;                            // 311,296 B
  unsigned short* KclsP = (unsigned short*)(f32r + 311296);  // 131,072 B
  unsigned short* VclsP = (unsigned short*)(f32r + 442368);  // 131,072 B
  unsigned short* wb1 = (unsigned short*)(f32r + 573440);    // 262,144 B
  unsigned short* wb2 = (unsigned short*)(f32r + 835584);    // 131,072 B
  unsigned short* wbo = (unsigned short*)(f32r + 966656);    // 262,144 B
  float* h1g = (float*)(f32r + 1228800);                     // 155,648 B
  float* bestg = (float*)(f32r + 1384448);                   // 131,072 B
  int* clsg = (int*)(f32r + 1515520);                        // 131,072 B
  unsigned int* Mu_part = (unsigned int*)(f32r + 1646592);   // 16,384 B
  unsigned int* cnt_part = (unsigned int*)(f32r + 1662976);  // 16,384 B
  float* Zf_part = (float*)(f32r + 1679360);                 // 16,384 B

  wk1a<<<448, 256, 0, stream>>>(q_w1, q_w2, o_w, wb1, wb2, wbo,
                                (uint4*)cls_feat, preds, bestg, clsg, Mu_part,
                                cnt_part);
  k1b<<<dim3(16, NB), 256, 0, stream>>>(bestg, clsg, Mu_part, Zf_part);
  xk2<<<dim3(8, 8, NB), 256, 0, stream>>>(x, bestg, clsg, Zf_part, xT,
                                          cls_feat);
  k3a<<<dim3(4, NB * NK), 256, 0, stream>>>(cls_feat, k_w1, k_g1, k_b1, v_w,
                                            v_g, v_b, h1g, VclsP);
  k3b<<<dim3(4, NB * NK), 256, 0, stream>>>(h1g, k_w2, k_g2, k_b2, KclsP);
  g1g2k5o<<<dim3(HW / 128, NB), 512, 0, stream>>>(xT, wb1, q_g1, q_b1, wb2,
                                                  q_g2, q_b2, KclsP, VclsP,
                                                  cnt_part, wbo, o_g, o_b,
                                                  out);
}